// Round 1
// baseline (3722.793 us; speedup 1.0000x reference)
//
#include <hip/hip_runtime.h>

#define ROWS 8192   // B*T
#define DD   1024   // d_model
#define TT   2048   // T
#define NH   16     // heads
#define HS   64     // head size

typedef __attribute__((ext_vector_type(8))) short short8;
typedef __attribute__((ext_vector_type(4))) float f32x4;
typedef __attribute__((ext_vector_type(4))) unsigned short us4;
typedef unsigned short u16;

__device__ __forceinline__ u16 f2bf(float f) {
  unsigned u = __builtin_bit_cast(unsigned, f);
  u += 0x7fffu + ((u >> 16) & 1u);   // round-to-nearest-even
  return (u16)(u >> 16);
}

__device__ __forceinline__ void gload16(const void* g, void* l) {
  __builtin_amdgcn_global_load_lds(
      (const __attribute__((address_space(1))) unsigned int*)g,
      (__attribute__((address_space(3))) unsigned int*)l, 16, 0, 0);
}

// ---------------- transpose + cast to bf16: WT[n][k] = bf16(W[k][n]) ----------------
__global__ __launch_bounds__(256) void transpose_cast(const float* __restrict__ W,
                                                      u16* __restrict__ WT) {
  __shared__ float tile[32][33];
  const int tx = threadIdx.x, ty = threadIdx.y;
  const int bx = blockIdx.x, by = blockIdx.y;
#pragma unroll
  for (int j = 0; j < 4; ++j)
    tile[ty + j * 8][tx] = W[(size_t)(by * 32 + ty + j * 8) * DD + bx * 32 + tx];
  __syncthreads();
#pragma unroll
  for (int j = 0; j < 4; ++j)
    WT[(size_t)(bx * 32 + ty + j * 8) * DD + by * 32 + tx] = f2bf(tile[tx][ty + j * 8]);
}

// ---------------- LayerNorm (pop. variance) + cast to bf16 ----------------
__global__ __launch_bounds__(256) void ln_kernel(const float* __restrict__ x,
                                                 const float* __restrict__ g,
                                                 const float* __restrict__ b,
                                                 u16* __restrict__ xn) {
  const int row = blockIdx.x;
  const int tid = threadIdx.x;
  const float4 v = reinterpret_cast<const float4*>(x + (size_t)row * DD)[tid];
  float s = v.x + v.y + v.z + v.w;
  float s2 = v.x * v.x + v.y * v.y + v.z * v.z + v.w * v.w;
#pragma unroll
  for (int o = 32; o > 0; o >>= 1) { s += __shfl_down(s, o); s2 += __shfl_down(s2, o); }
  __shared__ float red[8];
  const int wv = tid >> 6;
  if ((tid & 63) == 0) { red[wv] = s; red[4 + wv] = s2; }
  __syncthreads();
  s = red[0] + red[1] + red[2] + red[3];
  s2 = red[4] + red[5] + red[6] + red[7];
  const float mu = s * (1.f / 1024.f);
  const float var = s2 * (1.f / 1024.f) - mu * mu;
  const float rstd = rsqrtf(var + 1e-5f);
  const float4 gg = reinterpret_cast<const float4*>(g)[tid];
  const float4 bb = reinterpret_cast<const float4*>(b)[tid];
  us4 o4;
  o4.x = f2bf((v.x - mu) * rstd * gg.x + bb.x);
  o4.y = f2bf((v.y - mu) * rstd * gg.y + bb.y);
  o4.z = f2bf((v.z - mu) * rstd * gg.z + bb.z);
  o4.w = f2bf((v.w - mu) * rstd * gg.w + bb.w);
  *reinterpret_cast<us4*>(xn + (size_t)row * DD + tid * 4) = o4;
}

// ---------------- bf16 MFMA GEMM: C = A(MxK) @ BT(NxK)^T, epilogue per EPI ----------------
// EPI: 0 = store bf16, 1 = store f32, 2 = sigmoid f32, 3 = bias + (1-sigmoid) f32
template <int EPI>
__global__ __launch_bounds__(256) void gemm_bt(const u16* __restrict__ A,
                                               const u16* __restrict__ BT,
                                               float* __restrict__ Cf,
                                               u16* __restrict__ Cb,
                                               const float* __restrict__ bias,
                                               int M, int N, int K) {
  __shared__ u16 lA[2][128 * 32];
  __shared__ u16 lB[2][128 * 32];
  const int tid = threadIdx.x;
  const int bx = blockIdx.x, by = blockIdx.y;
  const int lane = tid & 63, wid = tid >> 6;
  const int wr = wid >> 1, wc = wid & 1;
  const int sr = tid >> 2, sc = (tid & 3) * 8;
  const u16* gA = A + (size_t)(by * 128 + sr) * K + sc;
  const u16* gB = BT + (size_t)(bx * 128 + sr) * K + sc;

  f32x4 acc[4][4];
#pragma unroll
  for (int m = 0; m < 4; ++m)
#pragma unroll
    for (int n = 0; n < 4; ++n) acc[m][n] = (f32x4){0.f, 0.f, 0.f, 0.f};

  auto stage = [&](int buf, int kt) {
    const u16* a0 = gA + kt * 32;
    const u16* b0 = gB + kt * 32;
    gload16(a0, &lA[buf][tid * 8]);
    gload16(a0 + (size_t)64 * K, &lA[buf][2048 + tid * 8]);
    gload16(b0, &lB[buf][tid * 8]);
    gload16(b0 + (size_t)64 * K, &lB[buf][2048 + tid * 8]);
  };

  stage(0, 0);
  const int fr = lane & 15, fk = (lane >> 4) * 8;
  int cur = 0;
  const int nk = K / 32;
  for (int kt = 0; kt < nk; ++kt) {
    __syncthreads();
    if (kt + 1 < nk) stage(cur ^ 1, kt + 1);
    short8 af[4], bv[4];
#pragma unroll
    for (int m = 0; m < 4; ++m)
      af[m] = *reinterpret_cast<const short8*>(&lA[cur][(wr * 64 + m * 16 + fr) * 32 + fk]);
#pragma unroll
    for (int n = 0; n < 4; ++n)
      bv[n] = *reinterpret_cast<const short8*>(&lB[cur][(wc * 64 + n * 16 + fr) * 32 + fk]);
#pragma unroll
    for (int m = 0; m < 4; ++m)
#pragma unroll
      for (int n = 0; n < 4; ++n)
        acc[m][n] = __builtin_amdgcn_mfma_f32_16x16x32_bf16(af[m], bv[n], acc[m][n], 0, 0, 0);
    cur ^= 1;
  }

  const int er = (lane >> 4) * 4, ec = lane & 15;
#pragma unroll
  for (int m = 0; m < 4; ++m) {
    const int row0 = by * 128 + wr * 64 + m * 16 + er;
#pragma unroll
    for (int n = 0; n < 4; ++n) {
      const int col = bx * 128 + wc * 64 + n * 16 + ec;
#pragma unroll
      for (int i = 0; i < 4; ++i) {
        const float val = acc[m][n][i];
        const size_t idx = (size_t)(row0 + i) * N + col;
        if constexpr (EPI == 0) {
          Cb[idx] = f2bf(val);
        } else if constexpr (EPI == 1) {
          Cf[idx] = val;
        } else if constexpr (EPI == 2) {
          Cf[idx] = 1.f / (1.f + __expf(-val));
        } else {
          const float z = val + bias[col];
          Cf[idx] = 1.f / (1.f + __expf(z));   // 1 - sigmoid(z)
        }
      }
    }
  }
}

// ---------------- sequential selective scan: 1 wave per (b,h) ----------------
__global__ __launch_bounds__(64) void scan_kernel(const float* __restrict__ omw,
                                                  const float* __restrict__ kk,
                                                  const float* __restrict__ vv,
                                                  const float* __restrict__ rr,
                                                  u16* __restrict__ outs,
                                                  float* __restrict__ stateOut) {
  const int bh = blockIdx.x;                 // b*16 + h
  const int e = threadIdx.x;                 // 0..63  (state column / v,out index)
  const size_t base0 = (size_t)(bh >> 4) * TT * DD + (size_t)(bh & 15) * HS;
  float st[64];
#pragma unroll
  for (int d = 0; d < 64; ++d) st[d] = 0.f;

  float ve = vv[base0 + e];
  size_t base = base0;
  for (int t = 0; t < TT; ++t) {
    const float* __restrict__ op = omw + base;  // wave-uniform addresses -> s_load
    const float* __restrict__ kp = kk + base;
    const float* __restrict__ rp = rr + base;
    const size_t nbase = (t + 1 < TT) ? (base + DD) : base0;  // always in-bounds
    const float ve_n = vv[nbase + e];

    float accv[4] = {0.f, 0.f, 0.f, 0.f};
#pragma unroll
    for (int j = 0; j < 16; ++j) {
#pragma unroll
      for (int c = 0; c < 4; ++c) {
        const int d = c * 16 + j;
        st[d] = __builtin_fmaf(op[d], st[d], kp[d] * ve);
        accv[c] = __builtin_fmaf(rp[d], st[d], accv[c]);
      }
    }
    outs[base + e] = f2bf((accv[0] + accv[1]) + (accv[2] + accv[3]));
    ve = ve_n;
    base += DD;
  }
#pragma unroll
  for (int d = 0; d < 64; ++d)
    stateOut[((size_t)bh * 64 + d) * 64 + e] = st[d];
}

extern "C" void kernel_launch(void* const* d_in, const int* in_sizes, int n_in,
                              void* d_out, int out_size, void* d_ws, size_t ws_size,
                              hipStream_t stream) {
  const float* x   = (const float*)d_in[0];
  const float* lng = (const float*)d_in[1];
  const float* lnb = (const float*)d_in[2];
  const float* Wx  = (const float*)d_in[3];
  const float* Ww  = (const float*)d_in[4];
  const float* bw  = (const float*)d_in[5];
  const float* Wk  = (const float*)d_in[6];
  const float* Wv  = (const float*)d_in[7];
  const float* Wr  = (const float*)d_in[8];
  const float* Wo  = (const float*)d_in[9];
  float* out = (float*)d_out;
  char* ws = (char*)d_ws;

  const size_t SZ_W = (size_t)DD * DD * 2;       // 2 MB bf16 weight
  u16* WxT = (u16*)(ws + 0 * SZ_W);
  u16* WwT = (u16*)(ws + 1 * SZ_W);
  u16* WkT = (u16*)(ws + 2 * SZ_W);
  u16* WvT = (u16*)(ws + 3 * SZ_W);
  u16* WrT = (u16*)(ws + 4 * SZ_W);
  u16* WoT = (u16*)(ws + 5 * SZ_W);
  size_t off = 6 * SZ_W;
  const size_t SZ_ABF = (size_t)ROWS * DD * 2;   // 16 MB bf16 activation
  u16* xn   = (u16*)(ws + off); off += SZ_ABF;
  u16* pbuf = (u16*)(ws + off); off += SZ_ABF;
  u16* outs = (u16*)(ws + off); off += SZ_ABF;
  const size_t SZ_AF = (size_t)ROWS * DD * 4;    // 32 MB f32 activation
  float* omw = (float*)(ws + off); off += SZ_AF;
  float* kf  = (float*)(ws + off); off += SZ_AF;
  float* vf  = (float*)(ws + off); off += SZ_AF;
  float* rf  = (float*)(ws + off); off += SZ_AF;
  (void)ws_size; (void)in_sizes; (void)n_in; (void)out_size;

  dim3 tpb(32, 8), tgrid(32, 32);
  transpose_cast<<<tgrid, tpb, 0, stream>>>(Wx, WxT);
  transpose_cast<<<tgrid, tpb, 0, stream>>>(Ww, WwT);
  transpose_cast<<<tgrid, tpb, 0, stream>>>(Wk, WkT);
  transpose_cast<<<tgrid, tpb, 0, stream>>>(Wv, WvT);
  transpose_cast<<<tgrid, tpb, 0, stream>>>(Wr, WrT);
  transpose_cast<<<tgrid, tpb, 0, stream>>>(Wo, WoT);

  ln_kernel<<<ROWS, 256, 0, stream>>>(x, lng, lnb, xn);

  dim3 ggrid(DD / 128, ROWS / 128), gblk(256);
  // p = xn @ Wx  (bf16)
  gemm_bt<0><<<ggrid, gblk, 0, stream>>>(xn, WxT, nullptr, pbuf, nullptr, ROWS, DD, DD);
  // omw = 1 - sigmoid(p @ Ww + bw)  (f32)
  gemm_bt<3><<<ggrid, gblk, 0, stream>>>(pbuf, WwT, omw, nullptr, bw, ROWS, DD, DD);
  // k, v (f32); r = sigmoid (f32)
  gemm_bt<1><<<ggrid, gblk, 0, stream>>>(xn, WkT, kf, nullptr, nullptr, ROWS, DD, DD);
  gemm_bt<1><<<ggrid, gblk, 0, stream>>>(xn, WvT, vf, nullptr, nullptr, ROWS, DD, DD);
  gemm_bt<2><<<ggrid, gblk, 0, stream>>>(xn, WrT, rf, nullptr, nullptr, ROWS, DD, DD);

  // sequential scan; writes outs (bf16) + final state (f32, second output)
  scan_kernel<<<64, 64, 0, stream>>>(omw, kf, vf, rf, outs, out + (size_t)ROWS * DD);

  // y = outs @ Wo (f32, first output)
  gemm_bt<1><<<ggrid, gblk, 0, stream>>>(outs, WoT, out, nullptr, nullptr, ROWS, DD, DD);
}

// Round 9
// 552.791 us; speedup vs baseline: 6.7345x; 6.7345x over previous
//
#include <hip/hip_runtime.h>

#define ROWS 8192   // B*T
#define DD   1024   // d_model
#define TT   2048   // T
#define NH   16     // heads
#define HS   64     // head size
#define CH   64     // scan chunk length
#define NC   (TT / CH)   // 32 chunks

typedef __attribute__((ext_vector_type(8))) short short8;
typedef __attribute__((ext_vector_type(4))) float f32x4;
typedef __attribute__((ext_vector_type(4))) unsigned short us4;
typedef unsigned short u16;

__device__ __forceinline__ u16 f2bf(float f) {
  unsigned u = __builtin_bit_cast(unsigned, f);
  u += 0x7fffu + ((u >> 16) & 1u);   // round-to-nearest-even
  return (u16)(u >> 16);
}

__device__ __forceinline__ void gload16(const void* g, void* l) {
  __builtin_amdgcn_global_load_lds(
      (const __attribute__((address_space(1))) unsigned int*)g,
      (__attribute__((address_space(3))) unsigned int*)l, 16, 0, 0);
}

// ---------------- transpose + cast to bf16: WT[n][k] = bf16(W[k][n]) ----------------
__global__ __launch_bounds__(256) void transpose_cast(const float* __restrict__ W,
                                                      u16* __restrict__ WT) {
  __shared__ float tile[32][33];
  const int tx = threadIdx.x, ty = threadIdx.y;
  const int bx = blockIdx.x, by = blockIdx.y;
#pragma unroll
  for (int j = 0; j < 4; ++j)
    tile[ty + j * 8][tx] = W[(size_t)(by * 32 + ty + j * 8) * DD + bx * 32 + tx];
  __syncthreads();
#pragma unroll
  for (int j = 0; j < 4; ++j)
    WT[(size_t)(bx * 32 + ty + j * 8) * DD + by * 32 + tx] = f2bf(tile[tx][ty + j * 8]);
}

// ---------------- LayerNorm (pop. variance) + cast to bf16 ----------------
__global__ __launch_bounds__(256) void ln_kernel(const float* __restrict__ x,
                                                 const float* __restrict__ g,
                                                 const float* __restrict__ b,
                                                 u16* __restrict__ xn) {
  const int row = blockIdx.x;
  const int tid = threadIdx.x;
  const float4 v = reinterpret_cast<const float4*>(x + (size_t)row * DD)[tid];
  float s = v.x + v.y + v.z + v.w;
  float s2 = v.x * v.x + v.y * v.y + v.z * v.z + v.w * v.w;
#pragma unroll
  for (int o = 32; o > 0; o >>= 1) { s += __shfl_down(s, o); s2 += __shfl_down(s2, o); }
  __shared__ float red[8];
  const int wv = tid >> 6;
  if ((tid & 63) == 0) { red[wv] = s; red[4 + wv] = s2; }
  __syncthreads();
  s = red[0] + red[1] + red[2] + red[3];
  s2 = red[4] + red[5] + red[6] + red[7];
  const float mu = s * (1.f / 1024.f);
  const float var = s2 * (1.f / 1024.f) - mu * mu;
  const float rstd = rsqrtf(var + 1e-5f);
  const float4 gg = reinterpret_cast<const float4*>(g)[tid];
  const float4 bb = reinterpret_cast<const float4*>(b)[tid];
  us4 o4;
  o4.x = f2bf((v.x - mu) * rstd * gg.x + bb.x);
  o4.y = f2bf((v.y - mu) * rstd * gg.y + bb.y);
  o4.z = f2bf((v.z - mu) * rstd * gg.z + bb.z);
  o4.w = f2bf((v.w - mu) * rstd * gg.w + bb.w);
  *reinterpret_cast<us4*>(xn + (size_t)row * DD + tid * 4) = o4;
}

// ---------------- bf16 MFMA GEMM: C = A(MxK) @ BT(NxK)^T, epilogue per EPI ----------------
// EPI: 0 = store bf16, 1 = store f32, 2 = sigmoid f32, 3 = bias + (1-sigmoid) f32
template <int EPI>
__global__ __launch_bounds__(256) void gemm_bt(const u16* __restrict__ A,
                                               const u16* __restrict__ BT,
                                               float* __restrict__ Cf,
                                               u16* __restrict__ Cb,
                                               const float* __restrict__ bias,
                                               int M, int N, int K) {
  __shared__ u16 lA[2][128 * 32];
  __shared__ u16 lB[2][128 * 32];
  const int tid = threadIdx.x;
  const int bx = blockIdx.x, by = blockIdx.y;
  const int lane = tid & 63, wid = tid >> 6;
  const int wr = wid >> 1, wc = wid & 1;
  const int sr = tid >> 2, sc = (tid & 3) * 8;
  const u16* gA = A + (size_t)(by * 128 + sr) * K + sc;
  const u16* gB = BT + (size_t)(bx * 128 + sr) * K + sc;

  f32x4 acc[4][4];
#pragma unroll
  for (int m = 0; m < 4; ++m)
#pragma unroll
    for (int n = 0; n < 4; ++n) acc[m][n] = (f32x4){0.f, 0.f, 0.f, 0.f};

  auto stage = [&](int buf, int kt) {
    const u16* a0 = gA + kt * 32;
    const u16* b0 = gB + kt * 32;
    gload16(a0, &lA[buf][tid * 8]);
    gload16(a0 + (size_t)64 * K, &lA[buf][2048 + tid * 8]);
    gload16(b0, &lB[buf][tid * 8]);
    gload16(b0 + (size_t)64 * K, &lB[buf][2048 + tid * 8]);
  };

  stage(0, 0);
  const int fr = lane & 15, fk = (lane >> 4) * 8;
  int cur = 0;
  const int nk = K / 32;
  for (int kt = 0; kt < nk; ++kt) {
    __syncthreads();
    if (kt + 1 < nk) stage(cur ^ 1, kt + 1);
    short8 af[4], bv[4];
#pragma unroll
    for (int m = 0; m < 4; ++m)
      af[m] = *reinterpret_cast<const short8*>(&lA[cur][(wr * 64 + m * 16 + fr) * 32 + fk]);
#pragma unroll
    for (int n = 0; n < 4; ++n)
      bv[n] = *reinterpret_cast<const short8*>(&lB[cur][(wc * 64 + n * 16 + fr) * 32 + fk]);
#pragma unroll
    for (int m = 0; m < 4; ++m)
#pragma unroll
      for (int n = 0; n < 4; ++n)
        acc[m][n] = __builtin_amdgcn_mfma_f32_16x16x32_bf16(af[m], bv[n], acc[m][n], 0, 0, 0);
    cur ^= 1;
  }

  const int er = (lane >> 4) * 4, ec = lane & 15;
#pragma unroll
  for (int m = 0; m < 4; ++m) {
    const int row0 = by * 128 + wr * 64 + m * 16 + er;
#pragma unroll
    for (int n = 0; n < 4; ++n) {
      const int col = bx * 128 + wc * 64 + n * 16 + ec;
#pragma unroll
      for (int i = 0; i < 4; ++i) {
        const float val = acc[m][n][i];
        const size_t idx = (size_t)(row0 + i) * N + col;
        if constexpr (EPI == 0) {
          Cb[idx] = f2bf(val);
        } else if constexpr (EPI == 1) {
          Cf[idx] = val;
        } else if constexpr (EPI == 2) {
          Cf[idx] = 1.f / (1.f + __expf(-val));
        } else {
          const float z = val + bias[col];
          Cf[idx] = 1.f / (1.f + __expf(z));   // 1 - sigmoid(z)
        }
      }
    }
  }
}

// ---------------- chunked scan, phase 1: per-chunk decay product P and zero-init state U ----
// grid (NC, 64 chains), 64 threads (lane = e / also lane = d for P)
__global__ __launch_bounds__(64) void scan_phase1(const float* __restrict__ omw,
                                                  const float* __restrict__ kk,
                                                  const float* __restrict__ vv,
                                                  float* __restrict__ U,
                                                  float* __restrict__ P) {
  const int c = blockIdx.x, bh = blockIdx.y;
  const int e = threadIdx.x;
  const size_t chainBase = (size_t)(bh >> 4) * TT * DD + (size_t)(bh & 15) * HS;
  size_t base = chainBase + (size_t)c * CH * DD;

  float st[64];
#pragma unroll
  for (int d = 0; d < 64; ++d) st[d] = 0.f;
  float p = 1.f;

  float ve = vv[base + e];
  for (int t = 0; t < CH; ++t) {
    const float* __restrict__ op = omw + base;  // wave-uniform -> s_load
    const float* __restrict__ kp = kk + base;
    const size_t nbase = (t + 1 < CH) ? (base + DD) : base;
    const float ve_n = vv[nbase + e];
    p *= op[e];                                  // per-lane d = e
#pragma unroll
    for (int j = 0; j < 16; ++j) {
#pragma unroll
      for (int cc = 0; cc < 4; ++cc) {
        const int d = cc * 16 + j;
        st[d] = __builtin_fmaf(op[d], st[d], kp[d] * ve);
      }
    }
    ve = ve_n;
    base += DD;
  }
  float* __restrict__ Ub = U + ((size_t)c * 64 + bh) * 4096;
#pragma unroll
  for (int d = 0; d < 64; ++d) Ub[d * 64 + e] = st[d];
  P[((size_t)c * 64 + bh) * 64 + e] = p;
}

// ---------------- phase 2: sequential combine over chunks (in-place: U becomes S_start) ----
// grid (64 chains, 16 d-slices), 256 threads; thread owns one (d,e) element
__global__ __launch_bounds__(256) void scan_phase2(float* __restrict__ U,
                                                   const float* __restrict__ P,
                                                   float* __restrict__ stateOut) {
  const int bh = blockIdx.x;
  const int ds = blockIdx.y;
  const int tid = threadIdx.x;
  const int d = ds * 4 + (tid >> 6);   // wave-uniform
  const int e = tid & 63;
  const size_t el = (size_t)d * 64 + e;

  float S = 0.f;
  size_t ub = (size_t)bh * 4096 + el;
  size_t pb = (size_t)bh * 64 + d;
  for (int c = 0; c < NC; ++c) {
    const float u_c = U[ub];
    const float p_c = P[pb];
    U[ub] = S;                              // chunk-start state (S_start)
    S = __builtin_fmaf(p_c, S, u_c);
    ub += (size_t)64 * 4096;
    pb += (size_t)64 * 64;
  }
  stateOut[(size_t)bh * 4096 + el] = S;   // final state (output 1)
}

// ---------------- phase 3: re-run chunk from true initial state, emit outputs ----------------
__global__ __launch_bounds__(64) void scan_phase3(const float* __restrict__ omw,
                                                  const float* __restrict__ kk,
                                                  const float* __restrict__ vv,
                                                  const float* __restrict__ rr,
                                                  const float* __restrict__ S_start,
                                                  u16* __restrict__ outs) {
  const int c = blockIdx.x, bh = blockIdx.y;
  const int e = threadIdx.x;
  const size_t chainBase = (size_t)(bh >> 4) * TT * DD + (size_t)(bh & 15) * HS;
  size_t base = chainBase + (size_t)c * CH * DD;

  float st[64];
  const float* __restrict__ Sb = S_start + ((size_t)c * 64 + bh) * 4096;
#pragma unroll
  for (int d = 0; d < 64; ++d) st[d] = Sb[d * 64 + e];

  float ve = vv[base + e];
  for (int t = 0; t < CH; ++t) {
    const float* __restrict__ op = omw + base;
    const float* __restrict__ kp = kk + base;
    const float* __restrict__ rp = rr + base;
    const size_t nbase = (t + 1 < CH) ? (base + DD) : base;
    const float ve_n = vv[nbase + e];

    float accv[4] = {0.f, 0.f, 0.f, 0.f};
#pragma unroll
    for (int j = 0; j < 16; ++j) {
#pragma unroll
      for (int cc = 0; cc < 4; ++cc) {
        const int d = cc * 16 + j;
        st[d] = __builtin_fmaf(op[d], st[d], kp[d] * ve);
        accv[cc] = __builtin_fmaf(rp[d], st[d], accv[cc]);
      }
    }
    outs[base + e] = f2bf((accv[0] + accv[1]) + (accv[2] + accv[3]));
    ve = ve_n;
    base += DD;
  }
}

extern "C" void kernel_launch(void* const* d_in, const int* in_sizes, int n_in,
                              void* d_out, int out_size, void* d_ws, size_t ws_size,
                              hipStream_t stream) {
  const float* x   = (const float*)d_in[0];
  const float* lng = (const float*)d_in[1];
  const float* lnb = (const float*)d_in[2];
  const float* Wx  = (const float*)d_in[3];
  const float* Ww  = (const float*)d_in[4];
  const float* bw  = (const float*)d_in[5];
  const float* Wk  = (const float*)d_in[6];
  const float* Wv  = (const float*)d_in[7];
  const float* Wr  = (const float*)d_in[8];
  const float* Wo  = (const float*)d_in[9];
  float* out = (float*)d_out;
  char* ws = (char*)d_ws;

  // ---- workspace layout: total 188 MiB, identical to the proven round-1 footprint ----
  const size_t SZ_W = (size_t)DD * DD * 2;       // 2 MB bf16 weight
  u16* WxT = (u16*)(ws + 0 * SZ_W);
  u16* WwT = (u16*)(ws + 1 * SZ_W);
  u16* WkT = (u16*)(ws + 2 * SZ_W);
  u16* WvT = (u16*)(ws + 3 * SZ_W);
  u16* WrT = (u16*)(ws + 4 * SZ_W);
  u16* WoT = (u16*)(ws + 5 * SZ_W);
  size_t off = 6 * SZ_W;
  const size_t SZ_ABF = (size_t)ROWS * DD * 2;   // 16 MB bf16 activation
  u16* xn   = (u16*)(ws + off); off += SZ_ABF;
  u16* pbuf = (u16*)(ws + off); off += SZ_ABF;
  u16* outs = (u16*)(ws + off); off += SZ_ABF;
  const size_t SZ_AF = (size_t)ROWS * DD * 4;    // 32 MB f32 activation
  float* omw = (float*)(ws + off); off += SZ_AF;
  float* kf  = (float*)(ws + off); off += SZ_AF;
  float* vf  = (float*)(ws + off); off += SZ_AF;
  float* rf  = (float*)(ws + off); off += SZ_AF;
  // scan scratch ALIASES dead buffers (no growth past 188 MiB):
  //  Ubuf (NC*64*4096*4 = 32 MiB) -> xn+pbuf region (dead after last projection GEMM;
  //    rewritten by ln_kernel every call, so graph-replay safe)
  //  Pbuf (NC*64*64*4 = 512 KiB)  -> WxT region (dead after GEMM 1; rewritten each call)
  float* Ubuf = (float*)xn;
  float* Pbuf = (float*)WxT;
  (void)ws_size; (void)in_sizes; (void)n_in; (void)out_size;

  dim3 tpb(32, 8), tgrid(32, 32);
  transpose_cast<<<tgrid, tpb, 0, stream>>>(Wx, WxT);
  transpose_cast<<<tgrid, tpb, 0, stream>>>(Ww, WwT);
  transpose_cast<<<tgrid, tpb, 0, stream>>>(Wk, WkT);
  transpose_cast<<<tgrid, tpb, 0, stream>>>(Wv, WvT);
  transpose_cast<<<tgrid, tpb, 0, stream>>>(Wr, WrT);
  transpose_cast<<<tgrid, tpb, 0, stream>>>(Wo, WoT);

  ln_kernel<<<ROWS, 256, 0, stream>>>(x, lng, lnb, xn);

  dim3 ggrid(DD / 128, ROWS / 128), gblk(256);
  // p = xn @ Wx  (bf16)
  gemm_bt<0><<<ggrid, gblk, 0, stream>>>(xn, WxT, nullptr, pbuf, nullptr, ROWS, DD, DD);
  // omw = 1 - sigmoid(p @ Ww + bw)  (f32)
  gemm_bt<3><<<ggrid, gblk, 0, stream>>>(pbuf, WwT, omw, nullptr, bw, ROWS, DD, DD);
  // k, v (f32); r = sigmoid (f32)
  gemm_bt<1><<<ggrid, gblk, 0, stream>>>(xn, WkT, kf, nullptr, nullptr, ROWS, DD, DD);
  gemm_bt<1><<<ggrid, gblk, 0, stream>>>(xn, WvT, vf, nullptr, nullptr, ROWS, DD, DD);
  gemm_bt<2><<<ggrid, gblk, 0, stream>>>(xn, WrT, rf, nullptr, nullptr, ROWS, DD, DD);

  // chunked scan (xn/pbuf/WxT are dead from here on; their memory hosts Ubuf/Pbuf)
  dim3 sgrid(NC, 64);
  scan_phase1<<<sgrid, 64, 0, stream>>>(omw, kf, vf, Ubuf, Pbuf);
  dim3 p2grid(64, 16);
  scan_phase2<<<p2grid, 256, 0, stream>>>(Ubuf, Pbuf, out + (size_t)ROWS * DD);
  scan_phase3<<<sgrid, 64, 0, stream>>>(omw, kf, vf, rf, Ubuf, outs);

  // y = outs @ Wo (f32, first output)
  gemm_bt<1><<<ggrid, gblk, 0, stream>>>(outs, WoT, out, nullptr, nullptr, ROWS, DD, DD);
}

// Round 10
// 515.510 us; speedup vs baseline: 7.2216x; 1.0723x over previous
//
#include <hip/hip_runtime.h>

#define ROWS 8192   // B*T
#define DD   1024   // d_model
#define TT   2048   // T
#define NH   16     // heads
#define HS   64     // head size
#define CH   64     // scan chunk length
#define NC   (TT / CH)   // 32 chunks

typedef __attribute__((ext_vector_type(8))) short short8;
typedef __attribute__((ext_vector_type(4))) float f32x4;
typedef __attribute__((ext_vector_type(4))) unsigned short us4;
typedef unsigned short u16;

__device__ __forceinline__ u16 f2bf(float f) {
  unsigned u = __builtin_bit_cast(unsigned, f);
  u += 0x7fffu + ((u >> 16) & 1u);   // round-to-nearest-even
  return (u16)(u >> 16);
}

__device__ __forceinline__ void gload16(const void* g, void* l) {
  __builtin_amdgcn_global_load_lds(
      (const __attribute__((address_space(1))) unsigned int*)g,
      (__attribute__((address_space(3))) unsigned int*)l, 16, 0, 0);
}

// ---------------- transpose + cast to bf16: WT[n][k] = bf16(W[k][n]) ----------------
__global__ __launch_bounds__(256) void transpose_cast(const float* __restrict__ W,
                                                      u16* __restrict__ WT) {
  __shared__ float tile[32][33];
  const int tx = threadIdx.x, ty = threadIdx.y;
  const int bx = blockIdx.x, by = blockIdx.y;
#pragma unroll
  for (int j = 0; j < 4; ++j)
    tile[ty + j * 8][tx] = W[(size_t)(by * 32 + ty + j * 8) * DD + bx * 32 + tx];
  __syncthreads();
#pragma unroll
  for (int j = 0; j < 4; ++j)
    WT[(size_t)(bx * 32 + ty + j * 8) * DD + by * 32 + tx] = f2bf(tile[tx][ty + j * 8]);
}

// ---------------- LayerNorm (pop. variance) + cast to bf16 ----------------
__global__ __launch_bounds__(256) void ln_kernel(const float* __restrict__ x,
                                                 const float* __restrict__ g,
                                                 const float* __restrict__ b,
                                                 u16* __restrict__ xn) {
  const int row = blockIdx.x;
  const int tid = threadIdx.x;
  const float4 v = reinterpret_cast<const float4*>(x + (size_t)row * DD)[tid];
  float s = v.x + v.y + v.z + v.w;
  float s2 = v.x * v.x + v.y * v.y + v.z * v.z + v.w * v.w;
#pragma unroll
  for (int o = 32; o > 0; o >>= 1) { s += __shfl_down(s, o); s2 += __shfl_down(s2, o); }
  __shared__ float red[8];
  const int wv = tid >> 6;
  if ((tid & 63) == 0) { red[wv] = s; red[4 + wv] = s2; }
  __syncthreads();
  s = red[0] + red[1] + red[2] + red[3];
  s2 = red[4] + red[5] + red[6] + red[7];
  const float mu = s * (1.f / 1024.f);
  const float var = s2 * (1.f / 1024.f) - mu * mu;
  const float rstd = rsqrtf(var + 1e-5f);
  const float4 gg = reinterpret_cast<const float4*>(g)[tid];
  const float4 bb = reinterpret_cast<const float4*>(b)[tid];
  us4 o4;
  o4.x = f2bf((v.x - mu) * rstd * gg.x + bb.x);
  o4.y = f2bf((v.y - mu) * rstd * gg.y + bb.y);
  o4.z = f2bf((v.z - mu) * rstd * gg.z + bb.z);
  o4.w = f2bf((v.w - mu) * rstd * gg.w + bb.w);
  *reinterpret_cast<us4*>(xn + (size_t)row * DD + tid * 4) = o4;
}

// ---------------- bf16 MFMA GEMM: C = A(MxK) @ BT(NxK)^T, epilogue per EPI ----------------
// EPI: 0 = store bf16, 1 = store f32, 2 = sigmoid f32, 3 = bias + (1-sigmoid) f32
template <int EPI>
__global__ __launch_bounds__(256) void gemm_bt(const u16* __restrict__ A,
                                               const u16* __restrict__ BT,
                                               float* __restrict__ Cf,
                                               u16* __restrict__ Cb,
                                               const float* __restrict__ bias,
                                               int M, int N, int K) {
  __shared__ u16 lA[2][128 * 32];
  __shared__ u16 lB[2][128 * 32];
  const int tid = threadIdx.x;
  const int bx = blockIdx.x, by = blockIdx.y;
  const int lane = tid & 63, wid = tid >> 6;
  const int wr = wid >> 1, wc = wid & 1;
  const int sr = tid >> 2, sc = (tid & 3) * 8;
  const u16* gA = A + (size_t)(by * 128 + sr) * K + sc;
  const u16* gB = BT + (size_t)(bx * 128 + sr) * K + sc;

  f32x4 acc[4][4];
#pragma unroll
  for (int m = 0; m < 4; ++m)
#pragma unroll
    for (int n = 0; n < 4; ++n) acc[m][n] = (f32x4){0.f, 0.f, 0.f, 0.f};

  auto stage = [&](int buf, int kt) {
    const u16* a0 = gA + kt * 32;
    const u16* b0 = gB + kt * 32;
    gload16(a0, &lA[buf][tid * 8]);
    gload16(a0 + (size_t)64 * K, &lA[buf][2048 + tid * 8]);
    gload16(b0, &lB[buf][tid * 8]);
    gload16(b0 + (size_t)64 * K, &lB[buf][2048 + tid * 8]);
  };

  stage(0, 0);
  const int fr = lane & 15, fk = (lane >> 4) * 8;
  int cur = 0;
  const int nk = K / 32;
  for (int kt = 0; kt < nk; ++kt) {
    __syncthreads();
    if (kt + 1 < nk) stage(cur ^ 1, kt + 1);
    short8 af[4], bv[4];
#pragma unroll
    for (int m = 0; m < 4; ++m)
      af[m] = *reinterpret_cast<const short8*>(&lA[cur][(wr * 64 + m * 16 + fr) * 32 + fk]);
#pragma unroll
    for (int n = 0; n < 4; ++n)
      bv[n] = *reinterpret_cast<const short8*>(&lB[cur][(wc * 64 + n * 16 + fr) * 32 + fk]);
#pragma unroll
    for (int m = 0; m < 4; ++m)
#pragma unroll
      for (int n = 0; n < 4; ++n)
        acc[m][n] = __builtin_amdgcn_mfma_f32_16x16x32_bf16(af[m], bv[n], acc[m][n], 0, 0, 0);
    cur ^= 1;
  }

  const int er = (lane >> 4) * 4, ec = lane & 15;
#pragma unroll
  for (int m = 0; m < 4; ++m) {
    const int row0 = by * 128 + wr * 64 + m * 16 + er;
#pragma unroll
    for (int n = 0; n < 4; ++n) {
      const int col = bx * 128 + wc * 64 + n * 16 + ec;
#pragma unroll
      for (int i = 0; i < 4; ++i) {
        const float val = acc[m][n][i];
        const size_t idx = (size_t)(row0 + i) * N + col;
        if constexpr (EPI == 0) {
          Cb[idx] = f2bf(val);
        } else if constexpr (EPI == 1) {
          Cf[idx] = val;
        } else if constexpr (EPI == 2) {
          Cf[idx] = 1.f / (1.f + __expf(-val));
        } else {
          const float z = val + bias[col];
          Cf[idx] = 1.f / (1.f + __expf(z));   // 1 - sigmoid(z)
        }
      }
    }
  }
}

// ---------------- chunked scan, phase 1: per-chunk decay product P and zero-init state U ----
// grid (NC, 64 chains), 256 threads = 4 waves; wave w owns d in [16w, 16w+16)
__global__ __launch_bounds__(256) void scan_phase1(const float* __restrict__ omw,
                                                   const float* __restrict__ kk,
                                                   const float* __restrict__ vv,
                                                   float* __restrict__ U,
                                                   float* __restrict__ P) {
  const int c = blockIdx.x, bh = blockIdx.y;
  const int tid = threadIdx.x;
  const int lane = tid & 63;                                    // e
  const int dbase = __builtin_amdgcn_readfirstlane((tid >> 6) << 4);
  const size_t chainBase = (size_t)(bh >> 4) * TT * DD + (size_t)(bh & 15) * HS;
  size_t base = chainBase + (size_t)c * CH * DD;

  float st[16];
#pragma unroll
  for (int i = 0; i < 16; ++i) st[i] = 0.f;
  const int pd = dbase + (lane & 15);
  float vp = 1.f;

  float ve = vv[base + lane];
  for (int t = 0; t < CH; ++t) {
    const float* __restrict__ op = omw + base;  // uniform + dbase -> s_load
    const float* __restrict__ kp = kk + base;
    const size_t nbase = (t + 1 < CH) ? (base + DD) : base;
    const float ve_n = vv[nbase + lane];
    vp *= op[pd];                                // per-lane vector load (16 uniq addrs)
#pragma unroll
    for (int i = 0; i < 16; ++i)
      st[i] = __builtin_fmaf(op[dbase + i], st[i], kp[dbase + i] * ve);
    ve = ve_n;
    base += DD;
  }
  float* __restrict__ Ub = U + ((size_t)c * 64 + bh) * 4096;
#pragma unroll
  for (int i = 0; i < 16; ++i) Ub[(dbase + i) * 64 + lane] = st[i];
  if (lane < 16) P[((size_t)c * 64 + bh) * 64 + dbase + lane] = vp;
}

// ---------------- phase 2: sequential combine over chunks (in-place: U becomes S_start) ----
// grid (64 chains, 16 d-slices), 256 threads; thread owns one (d,e) element
__global__ __launch_bounds__(256) void scan_phase2(float* __restrict__ U,
                                                   const float* __restrict__ P,
                                                   float* __restrict__ stateOut) {
  const int bh = blockIdx.x;
  const int ds = blockIdx.y;
  const int tid = threadIdx.x;
  const int d = ds * 4 + (tid >> 6);   // wave-uniform
  const int e = tid & 63;
  const size_t el = (size_t)d * 64 + e;

  float S = 0.f;
  size_t ub = (size_t)bh * 4096 + el;
  size_t pb = (size_t)bh * 64 + d;
  for (int c = 0; c < NC; ++c) {
    const float u_c = U[ub];
    const float p_c = P[pb];
    U[ub] = S;                              // chunk-start state (S_start)
    S = __builtin_fmaf(p_c, S, u_c);
    ub += (size_t)64 * 4096;
    pb += (size_t)64 * 64;
  }
  stateOut[(size_t)bh * 4096 + el] = S;   // final state (output 1)
}

// ---------------- phase 3: re-run chunk from true initial state, emit outputs ----------------
// grid (NC, 64 chains), 256 threads = 4 waves; wave w owns d in [16w, 16w+16);
// per-step LDS partial-sum reduce (double-buffered), wave 0 stores out.
__global__ __launch_bounds__(256) void scan_phase3(const float* __restrict__ omw,
                                                   const float* __restrict__ kk,
                                                   const float* __restrict__ vv,
                                                   const float* __restrict__ rr,
                                                   const float* __restrict__ S_start,
                                                   u16* __restrict__ outs) {
  __shared__ float part[2][4][64];
  const int c = blockIdx.x, bh = blockIdx.y;
  const int tid = threadIdx.x;
  const int lane = tid & 63;                 // e
  const int wid = tid >> 6;
  const int dbase = __builtin_amdgcn_readfirstlane(wid << 4);
  const size_t chainBase = (size_t)(bh >> 4) * TT * DD + (size_t)(bh & 15) * HS;
  size_t base = chainBase + (size_t)c * CH * DD;

  float st[16];
  const float* __restrict__ Sb = S_start + ((size_t)c * 64 + bh) * 4096;
#pragma unroll
  for (int i = 0; i < 16; ++i) st[i] = Sb[(dbase + i) * 64 + lane];

  float ve = vv[base + lane];
  for (int t = 0; t < CH; ++t) {
    const float* __restrict__ op = omw + base;
    const float* __restrict__ kp = kk + base;
    const float* __restrict__ rp = rr + base;
    const size_t nbase = (t + 1 < CH) ? (base + DD) : base;
    const float ve_n = vv[nbase + lane];

    float a0 = 0.f, a1 = 0.f, a2 = 0.f, a3 = 0.f;
#pragma unroll
    for (int i = 0; i < 4; ++i) {
      st[i] = __builtin_fmaf(op[dbase + i], st[i], kp[dbase + i] * ve);
      a0 = __builtin_fmaf(rp[dbase + i], st[i], a0);
      st[4 + i] = __builtin_fmaf(op[dbase + 4 + i], st[4 + i], kp[dbase + 4 + i] * ve);
      a1 = __builtin_fmaf(rp[dbase + 4 + i], st[4 + i], a1);
      st[8 + i] = __builtin_fmaf(op[dbase + 8 + i], st[8 + i], kp[dbase + 8 + i] * ve);
      a2 = __builtin_fmaf(rp[dbase + 8 + i], st[8 + i], a2);
      st[12 + i] = __builtin_fmaf(op[dbase + 12 + i], st[12 + i], kp[dbase + 12 + i] * ve);
      a3 = __builtin_fmaf(rp[dbase + 12 + i], st[12 + i], a3);
    }
    part[t & 1][wid][lane] = (a0 + a1) + (a2 + a3);
    __syncthreads();
    if (wid == 0) {
      const float s = (part[t & 1][0][lane] + part[t & 1][1][lane]) +
                      (part[t & 1][2][lane] + part[t & 1][3][lane]);
      outs[base + lane] = f2bf(s);
    }
    ve = ve_n;
    base += DD;
  }
}

extern "C" void kernel_launch(void* const* d_in, const int* in_sizes, int n_in,
                              void* d_out, int out_size, void* d_ws, size_t ws_size,
                              hipStream_t stream) {
  const float* x   = (const float*)d_in[0];
  const float* lng = (const float*)d_in[1];
  const float* lnb = (const float*)d_in[2];
  const float* Wx  = (const float*)d_in[3];
  const float* Ww  = (const float*)d_in[4];
  const float* bw  = (const float*)d_in[5];
  const float* Wk  = (const float*)d_in[6];
  const float* Wv  = (const float*)d_in[7];
  const float* Wr  = (const float*)d_in[8];
  const float* Wo  = (const float*)d_in[9];
  float* out = (float*)d_out;
  char* ws = (char*)d_ws;

  // ---- workspace layout: total 188 MiB, identical to the proven round-1 footprint ----
  const size_t SZ_W = (size_t)DD * DD * 2;       // 2 MB bf16 weight
  u16* WxT = (u16*)(ws + 0 * SZ_W);
  u16* WwT = (u16*)(ws + 1 * SZ_W);
  u16* WkT = (u16*)(ws + 2 * SZ_W);
  u16* WvT = (u16*)(ws + 3 * SZ_W);
  u16* WrT = (u16*)(ws + 4 * SZ_W);
  u16* WoT = (u16*)(ws + 5 * SZ_W);
  size_t off = 6 * SZ_W;
  const size_t SZ_ABF = (size_t)ROWS * DD * 2;   // 16 MB bf16 activation
  u16* xn   = (u16*)(ws + off); off += SZ_ABF;
  u16* pbuf = (u16*)(ws + off); off += SZ_ABF;
  u16* outs = (u16*)(ws + off); off += SZ_ABF;
  const size_t SZ_AF = (size_t)ROWS * DD * 4;    // 32 MB f32 activation
  float* omw = (float*)(ws + off); off += SZ_AF;
  float* kf  = (float*)(ws + off); off += SZ_AF;
  float* vf  = (float*)(ws + off); off += SZ_AF;
  float* rf  = (float*)(ws + off); off += SZ_AF;
  // scan scratch ALIASES dead buffers (no growth past 188 MiB):
  //  Ubuf (NC*64*4096*4 = 32 MiB) -> xn+pbuf region (dead after last projection GEMM;
  //    rewritten by ln_kernel every call, so graph-replay safe)
  //  Pbuf (NC*64*64*4 = 512 KiB)  -> WxT region (dead after GEMM 1; rewritten each call)
  float* Ubuf = (float*)xn;
  float* Pbuf = (float*)WxT;
  (void)ws_size; (void)in_sizes; (void)n_in; (void)out_size;

  dim3 tpb(32, 8), tgrid(32, 32);
  transpose_cast<<<tgrid, tpb, 0, stream>>>(Wx, WxT);
  transpose_cast<<<tgrid, tpb, 0, stream>>>(Ww, WwT);
  transpose_cast<<<tgrid, tpb, 0, stream>>>(Wk, WkT);
  transpose_cast<<<tgrid, tpb, 0, stream>>>(Wv, WvT);
  transpose_cast<<<tgrid, tpb, 0, stream>>>(Wr, WrT);
  transpose_cast<<<tgrid, tpb, 0, stream>>>(Wo, WoT);

  ln_kernel<<<ROWS, 256, 0, stream>>>(x, lng, lnb, xn);

  dim3 ggrid(DD / 128, ROWS / 128), gblk(256);
  // p = xn @ Wx  (bf16)
  gemm_bt<0><<<ggrid, gblk, 0, stream>>>(xn, WxT, nullptr, pbuf, nullptr, ROWS, DD, DD);
  // omw = 1 - sigmoid(p @ Ww + bw)  (f32)
  gemm_bt<3><<<ggrid, gblk, 0, stream>>>(pbuf, WwT, omw, nullptr, bw, ROWS, DD, DD);
  // k, v (f32); r = sigmoid (f32)
  gemm_bt<1><<<ggrid, gblk, 0, stream>>>(xn, WkT, kf, nullptr, nullptr, ROWS, DD, DD);
  gemm_bt<1><<<ggrid, gblk, 0, stream>>>(xn, WvT, vf, nullptr, nullptr, ROWS, DD, DD);
  gemm_bt<2><<<ggrid, gblk, 0, stream>>>(xn, WrT, rf, nullptr, nullptr, ROWS, DD, DD);

  // chunked scan (xn/pbuf/WxT are dead from here on; their memory hosts Ubuf/Pbuf)
  dim3 sgrid(NC, 64);
  scan_phase1<<<sgrid, 256, 0, stream>>>(omw, kf, vf, Ubuf, Pbuf);
  dim3 p2grid(64, 16);
  scan_phase2<<<p2grid, 256, 0, stream>>>(Ubuf, Pbuf, out + (size_t)ROWS * DD);
  scan_phase3<<<sgrid, 256, 0, stream>>>(omw, kf, vf, rf, Ubuf, outs);

  // y = outs @ Wo (f32, first output)
  gemm_bt<1><<<ggrid, gblk, 0, stream>>>(outs, WoT, out, nullptr, nullptr, ROWS, DD, DD);
}

// Round 11
// 505.356 us; speedup vs baseline: 7.3667x; 1.0201x over previous
//
#include <hip/hip_runtime.h>

#define ROWS 8192   // B*T
#define DD   1024   // d_model
#define TT   2048   // T
#define NH   16     // heads
#define HS   64     // head size
#define CH   32     // scan chunk length
#define NC   (TT / CH)   // 64 chunks

typedef __attribute__((ext_vector_type(8))) short short8;
typedef __attribute__((ext_vector_type(4))) float f32x4;
typedef __attribute__((ext_vector_type(4))) unsigned short us4;
typedef unsigned short u16;

__device__ __forceinline__ u16 f2bf(float f) {
  unsigned u = __builtin_bit_cast(unsigned, f);
  u += 0x7fffu + ((u >> 16) & 1u);   // round-to-nearest-even
  return (u16)(u >> 16);
}

__device__ __forceinline__ float bf2f(u16 h) {
  return __builtin_bit_cast(float, (unsigned)h << 16);
}

__device__ __forceinline__ void gload16(const void* g, void* l) {
  __builtin_amdgcn_global_load_lds(
      (const __attribute__((address_space(1))) unsigned int*)g,
      (__attribute__((address_space(3))) unsigned int*)l, 16, 0, 0);
}

// ---------------- transpose + cast to bf16: WT[n][k] = bf16(W[k][n]) ----------------
__global__ __launch_bounds__(256) void transpose_cast(const float* __restrict__ W,
                                                      u16* __restrict__ WT) {
  __shared__ float tile[32][33];
  const int tx = threadIdx.x, ty = threadIdx.y;
  const int bx = blockIdx.x, by = blockIdx.y;
#pragma unroll
  for (int j = 0; j < 4; ++j)
    tile[ty + j * 8][tx] = W[(size_t)(by * 32 + ty + j * 8) * DD + bx * 32 + tx];
  __syncthreads();
#pragma unroll
  for (int j = 0; j < 4; ++j)
    WT[(size_t)(bx * 32 + ty + j * 8) * DD + by * 32 + tx] = f2bf(tile[tx][ty + j * 8]);
}

// ---------------- LayerNorm (pop. variance) + cast to bf16 ----------------
__global__ __launch_bounds__(256) void ln_kernel(const float* __restrict__ x,
                                                 const float* __restrict__ g,
                                                 const float* __restrict__ b,
                                                 u16* __restrict__ xn) {
  const int row = blockIdx.x;
  const int tid = threadIdx.x;
  const float4 v = reinterpret_cast<const float4*>(x + (size_t)row * DD)[tid];
  float s = v.x + v.y + v.z + v.w;
  float s2 = v.x * v.x + v.y * v.y + v.z * v.z + v.w * v.w;
#pragma unroll
  for (int o = 32; o > 0; o >>= 1) { s += __shfl_down(s, o); s2 += __shfl_down(s2, o); }
  __shared__ float red[8];
  const int wv = tid >> 6;
  if ((tid & 63) == 0) { red[wv] = s; red[4 + wv] = s2; }
  __syncthreads();
  s = red[0] + red[1] + red[2] + red[3];
  s2 = red[4] + red[5] + red[6] + red[7];
  const float mu = s * (1.f / 1024.f);
  const float var = s2 * (1.f / 1024.f) - mu * mu;
  const float rstd = rsqrtf(var + 1e-5f);
  const float4 gg = reinterpret_cast<const float4*>(g)[tid];
  const float4 bb = reinterpret_cast<const float4*>(b)[tid];
  us4 o4;
  o4.x = f2bf((v.x - mu) * rstd * gg.x + bb.x);
  o4.y = f2bf((v.y - mu) * rstd * gg.y + bb.y);
  o4.z = f2bf((v.z - mu) * rstd * gg.z + bb.z);
  o4.w = f2bf((v.w - mu) * rstd * gg.w + bb.w);
  *reinterpret_cast<us4*>(xn + (size_t)row * DD + tid * 4) = o4;
}

// ---------------- bf16 MFMA GEMM: C = A(MxK) @ BT(NxK)^T, epilogue per EPI ----------------
// EPI: 0 = store bf16, 1 = store f32, 2 = sigmoid f32, 3 = bias + (1-sigmoid) f32
template <int EPI>
__global__ __launch_bounds__(256) void gemm_bt(const u16* __restrict__ A,
                                               const u16* __restrict__ BT,
                                               float* __restrict__ Cf,
                                               u16* __restrict__ Cb,
                                               const float* __restrict__ bias,
                                               int M, int N, int K) {
  __shared__ u16 lA[2][128 * 32];
  __shared__ u16 lB[2][128 * 32];
  const int tid = threadIdx.x;
  const int bx = blockIdx.x, by = blockIdx.y;
  const int lane = tid & 63, wid = tid >> 6;
  const int wr = wid >> 1, wc = wid & 1;
  const int sr = tid >> 2, sc = (tid & 3) * 8;
  const u16* gA = A + (size_t)(by * 128 + sr) * K + sc;
  const u16* gB = BT + (size_t)(bx * 128 + sr) * K + sc;

  f32x4 acc[4][4];
#pragma unroll
  for (int m = 0; m < 4; ++m)
#pragma unroll
    for (int n = 0; n < 4; ++n) acc[m][n] = (f32x4){0.f, 0.f, 0.f, 0.f};

  auto stage = [&](int buf, int kt) {
    const u16* a0 = gA + kt * 32;
    const u16* b0 = gB + kt * 32;
    gload16(a0, &lA[buf][tid * 8]);
    gload16(a0 + (size_t)64 * K, &lA[buf][2048 + tid * 8]);
    gload16(b0, &lB[buf][tid * 8]);
    gload16(b0 + (size_t)64 * K, &lB[buf][2048 + tid * 8]);
  };

  stage(0, 0);
  const int fr = lane & 15, fk = (lane >> 4) * 8;
  int cur = 0;
  const int nk = K / 32;
  for (int kt = 0; kt < nk; ++kt) {
    __syncthreads();
    if (kt + 1 < nk) stage(cur ^ 1, kt + 1);
    short8 af[4], bv[4];
#pragma unroll
    for (int m = 0; m < 4; ++m)
      af[m] = *reinterpret_cast<const short8*>(&lA[cur][(wr * 64 + m * 16 + fr) * 32 + fk]);
#pragma unroll
    for (int n = 0; n < 4; ++n)
      bv[n] = *reinterpret_cast<const short8*>(&lB[cur][(wc * 64 + n * 16 + fr) * 32 + fk]);
#pragma unroll
    for (int m = 0; m < 4; ++m)
#pragma unroll
      for (int n = 0; n < 4; ++n)
        acc[m][n] = __builtin_amdgcn_mfma_f32_16x16x32_bf16(af[m], bv[n], acc[m][n], 0, 0, 0);
    cur ^= 1;
  }

  const int er = (lane >> 4) * 4, ec = lane & 15;
#pragma unroll
  for (int m = 0; m < 4; ++m) {
    const int row0 = by * 128 + wr * 64 + m * 16 + er;
#pragma unroll
    for (int n = 0; n < 4; ++n) {
      const int col = bx * 128 + wc * 64 + n * 16 + ec;
#pragma unroll
      for (int i = 0; i < 4; ++i) {
        const float val = acc[m][n][i];
        const size_t idx = (size_t)(row0 + i) * N + col;
        if constexpr (EPI == 0) {
          Cb[idx] = f2bf(val);
        } else if constexpr (EPI == 1) {
          Cf[idx] = val;
        } else if constexpr (EPI == 2) {
          Cf[idx] = 1.f / (1.f + __expf(-val));
        } else {
          const float z = val + bias[col];
          Cf[idx] = 1.f / (1.f + __expf(z));   // 1 - sigmoid(z)
        }
      }
    }
  }
}

// ---------------- chunked scan, phase 1: per-chunk decay product P and zero-init state U ----
// grid (NC, 64 chains), 64 threads = 1 wave (barrier-free); U stored bf16
__global__ __launch_bounds__(64) void scan_phase1(const float* __restrict__ omw,
                                                  const float* __restrict__ kk,
                                                  const float* __restrict__ vv,
                                                  u16* __restrict__ U,
                                                  float* __restrict__ P) {
  const int c = blockIdx.x, bh = blockIdx.y;
  const int e = threadIdx.x;
  const size_t chainBase = (size_t)(bh >> 4) * TT * DD + (size_t)(bh & 15) * HS;
  size_t base = chainBase + (size_t)c * CH * DD;

  float st[64];
#pragma unroll
  for (int d = 0; d < 64; ++d) st[d] = 0.f;
  float p = 1.f;

  float ve = vv[base + e];
  for (int t = 0; t < CH; ++t) {
    const float* __restrict__ op = omw + base;  // wave-uniform -> s_load
    const float* __restrict__ kp = kk + base;
    const size_t nbase = (t + 1 < CH) ? (base + DD) : base;
    const float ve_n = vv[nbase + e];
    p *= op[e];                                  // per-lane d = e
#pragma unroll
    for (int j = 0; j < 16; ++j) {
#pragma unroll
      for (int cc = 0; cc < 4; ++cc) {
        const int d = cc * 16 + j;
        st[d] = __builtin_fmaf(op[d], st[d], kp[d] * ve);
      }
    }
    ve = ve_n;
    base += DD;
  }
  u16* __restrict__ Ub = U + ((size_t)c * 64 + bh) * 4096;
#pragma unroll
  for (int d = 0; d < 64; ++d) Ub[d * 64 + e] = f2bf(st[d]);
  P[((size_t)c * 64 + bh) * 64 + e] = p;
}

// ---------------- phase 2: sequential combine over chunks (in-place: U becomes S_start) ----
// grid (64 chains, 16 d-slices), 256 threads; thread owns one (d,e) element; fp32 accum
__global__ __launch_bounds__(256) void scan_phase2(u16* __restrict__ U,
                                                   const float* __restrict__ P,
                                                   float* __restrict__ stateOut) {
  const int bh = blockIdx.x;
  const int ds = blockIdx.y;
  const int tid = threadIdx.x;
  const int d = ds * 4 + (tid >> 6);   // wave-uniform
  const int e = tid & 63;
  const size_t el = (size_t)d * 64 + e;

  float S = 0.f;
  size_t ub = (size_t)bh * 4096 + el;
  size_t pb = (size_t)bh * 64 + d;
  u16 u_c = U[ub];
  float p_c = P[pb];
  for (int c = 0; c < NC; ++c) {
    u16 u_n = u_c; float p_n = p_c;
    if (c + 1 < NC) {                        // prefetch next chunk's inputs
      u_n = U[ub + (size_t)64 * 4096];
      p_n = P[pb + (size_t)64 * 64];
    }
    U[ub] = f2bf(S);                         // chunk-start state (S_start)
    S = __builtin_fmaf(p_c, S, bf2f(u_c));
    u_c = u_n; p_c = p_n;
    ub += (size_t)64 * 4096;
    pb += (size_t)64 * 64;
  }
  stateOut[(size_t)bh * 4096 + el] = S;   // final state (output 1)
}

// ---------------- phase 3: re-run chunk from true initial state, emit outputs ----------------
// grid (NC, 64 chains), 64 threads = 1 wave (barrier-free); S_start read as bf16
__global__ __launch_bounds__(64) void scan_phase3(const float* __restrict__ omw,
                                                  const float* __restrict__ kk,
                                                  const float* __restrict__ vv,
                                                  const float* __restrict__ rr,
                                                  const u16* __restrict__ S_start,
                                                  u16* __restrict__ outs) {
  const int c = blockIdx.x, bh = blockIdx.y;
  const int e = threadIdx.x;
  const size_t chainBase = (size_t)(bh >> 4) * TT * DD + (size_t)(bh & 15) * HS;
  size_t base = chainBase + (size_t)c * CH * DD;

  float st[64];
  const u16* __restrict__ Sb = S_start + ((size_t)c * 64 + bh) * 4096;
#pragma unroll
  for (int d = 0; d < 64; ++d) st[d] = bf2f(Sb[d * 64 + e]);

  float ve = vv[base + e];
  for (int t = 0; t < CH; ++t) {
    const float* __restrict__ op = omw + base;
    const float* __restrict__ kp = kk + base;
    const float* __restrict__ rp = rr + base;
    const size_t nbase = (t + 1 < CH) ? (base + DD) : base;
    const float ve_n = vv[nbase + e];

    float accv[4] = {0.f, 0.f, 0.f, 0.f};
#pragma unroll
    for (int j = 0; j < 16; ++j) {
#pragma unroll
      for (int cc = 0; cc < 4; ++cc) {
        const int d = cc * 16 + j;
        st[d] = __builtin_fmaf(op[d], st[d], kp[d] * ve);
        accv[cc] = __builtin_fmaf(rp[d], st[d], accv[cc]);
      }
    }
    outs[base + e] = f2bf((accv[0] + accv[1]) + (accv[2] + accv[3]));
    ve = ve_n;
    base += DD;
  }
}

extern "C" void kernel_launch(void* const* d_in, const int* in_sizes, int n_in,
                              void* d_out, int out_size, void* d_ws, size_t ws_size,
                              hipStream_t stream) {
  const float* x   = (const float*)d_in[0];
  const float* lng = (const float*)d_in[1];
  const float* lnb = (const float*)d_in[2];
  const float* Wx  = (const float*)d_in[3];
  const float* Ww  = (const float*)d_in[4];
  const float* bw  = (const float*)d_in[5];
  const float* Wk  = (const float*)d_in[6];
  const float* Wv  = (const float*)d_in[7];
  const float* Wr  = (const float*)d_in[8];
  const float* Wo  = (const float*)d_in[9];
  float* out = (float*)d_out;
  char* ws = (char*)d_ws;

  // ---- workspace layout: total 188 MiB, identical to the proven round-1 footprint ----
  const size_t SZ_W = (size_t)DD * DD * 2;       // 2 MB bf16 weight
  u16* WxT = (u16*)(ws + 0 * SZ_W);
  u16* WwT = (u16*)(ws + 1 * SZ_W);
  u16* WkT = (u16*)(ws + 2 * SZ_W);
  u16* WvT = (u16*)(ws + 3 * SZ_W);
  u16* WrT = (u16*)(ws + 4 * SZ_W);
  u16* WoT = (u16*)(ws + 5 * SZ_W);
  size_t off = 6 * SZ_W;
  const size_t SZ_ABF = (size_t)ROWS * DD * 2;   // 16 MB bf16 activation
  u16* xn   = (u16*)(ws + off); off += SZ_ABF;
  u16* pbuf = (u16*)(ws + off); off += SZ_ABF;
  u16* outs = (u16*)(ws + off); off += SZ_ABF;
  const size_t SZ_AF = (size_t)ROWS * DD * 4;    // 32 MB f32 activation
  float* omw = (float*)(ws + off); off += SZ_AF;
  float* kf  = (float*)(ws + off); off += SZ_AF;
  float* vf  = (float*)(ws + off); off += SZ_AF;
  float* rf  = (float*)(ws + off); off += SZ_AF;
  // scan scratch ALIASES dead buffers (no growth past 188 MiB):
  //  Ubuf bf16 (NC*64*4096*2 = 32 MiB) -> xn+pbuf region (dead after last projection
  //    GEMM; rewritten by ln_kernel every call, so graph-replay safe)
  //  Pbuf fp32 (NC*64*64*4 = 1 MiB)    -> WxT region (dead after GEMM 1)
  u16*   Ubuf = xn;
  float* Pbuf = (float*)WxT;
  (void)ws_size; (void)in_sizes; (void)n_in; (void)out_size;

  dim3 tpb(32, 8), tgrid(32, 32);
  transpose_cast<<<tgrid, tpb, 0, stream>>>(Wx, WxT);
  transpose_cast<<<tgrid, tpb, 0, stream>>>(Ww, WwT);
  transpose_cast<<<tgrid, tpb, 0, stream>>>(Wk, WkT);
  transpose_cast<<<tgrid, tpb, 0, stream>>>(Wv, WvT);
  transpose_cast<<<tgrid, tpb, 0, stream>>>(Wr, WrT);
  transpose_cast<<<tgrid, tpb, 0, stream>>>(Wo, WoT);

  ln_kernel<<<ROWS, 256, 0, stream>>>(x, lng, lnb, xn);

  dim3 ggrid(DD / 128, ROWS / 128), gblk(256);
  // p = xn @ Wx  (bf16)
  gemm_bt<0><<<ggrid, gblk, 0, stream>>>(xn, WxT, nullptr, pbuf, nullptr, ROWS, DD, DD);
  // omw = 1 - sigmoid(p @ Ww + bw)  (f32)
  gemm_bt<3><<<ggrid, gblk, 0, stream>>>(pbuf, WwT, omw, nullptr, bw, ROWS, DD, DD);
  // k, v (f32); r = sigmoid (f32)
  gemm_bt<1><<<ggrid, gblk, 0, stream>>>(xn, WkT, kf, nullptr, nullptr, ROWS, DD, DD);
  gemm_bt<1><<<ggrid, gblk, 0, stream>>>(xn, WvT, vf, nullptr, nullptr, ROWS, DD, DD);
  gemm_bt<2><<<ggrid, gblk, 0, stream>>>(xn, WrT, rf, nullptr, nullptr, ROWS, DD, DD);

  // chunked scan (xn/pbuf/WxT are dead from here on; their memory hosts Ubuf/Pbuf)
  dim3 sgrid(NC, 64);
  scan_phase1<<<sgrid, 64, 0, stream>>>(omw, kf, vf, Ubuf, Pbuf);
  dim3 p2grid(64, 16);
  scan_phase2<<<p2grid, 256, 0, stream>>>(Ubuf, Pbuf, out + (size_t)ROWS * DD);
  scan_phase3<<<sgrid, 64, 0, stream>>>(omw, kf, vf, rf, Ubuf, outs);

  // y = outs @ Wo (f32, first output)
  gemm_bt<1><<<ggrid, gblk, 0, stream>>>(outs, WoT, out, nullptr, nullptr, ROWS, DD, DD);
}

// Round 16
// 495.756 us; speedup vs baseline: 7.5093x; 1.0194x over previous
//
#include <hip/hip_runtime.h>

#define ROWS 8192   // B*T
#define DD   1024   // d_model
#define TT   2048   // T
#define NH   16     // heads
#define HS   64     // head size
#define CH   32     // scan chunk length
#define NC   (TT / CH)   // 64 chunks

typedef __attribute__((ext_vector_type(8))) short short8;
typedef __attribute__((ext_vector_type(4))) float f32x4;
typedef __attribute__((ext_vector_type(4))) unsigned short us4;
typedef unsigned short u16;

__device__ __forceinline__ u16 f2bf(float f) {
  unsigned u = __builtin_bit_cast(unsigned, f);
  u += 0x7fffu + ((u >> 16) & 1u);   // round-to-nearest-even
  return (u16)(u >> 16);
}

__device__ __forceinline__ float bf2f(u16 h) {
  return __builtin_bit_cast(float, (unsigned)h << 16);
}

__device__ __forceinline__ void gload16(const void* g, void* l) {
  __builtin_amdgcn_global_load_lds(
      (const __attribute__((address_space(1))) unsigned int*)g,
      (__attribute__((address_space(3))) unsigned int*)l, 16, 0, 0);
}

// ---------------- transpose + cast to bf16: WT[n][k] = bf16(W[k][n]) ----------------
__global__ __launch_bounds__(256) void transpose_cast(const float* __restrict__ W,
                                                      u16* __restrict__ WT) {
  __shared__ float tile[32][33];
  const int tx = threadIdx.x, ty = threadIdx.y;
  const int bx = blockIdx.x, by = blockIdx.y;
#pragma unroll
  for (int j = 0; j < 4; ++j)
    tile[ty + j * 8][tx] = W[(size_t)(by * 32 + ty + j * 8) * DD + bx * 32 + tx];
  __syncthreads();
#pragma unroll
  for (int j = 0; j < 4; ++j)
    WT[(size_t)(bx * 32 + ty + j * 8) * DD + by * 32 + tx] = f2bf(tile[tx][ty + j * 8]);
}

// ---------------- LayerNorm (pop. variance) + cast to bf16 ----------------
__global__ __launch_bounds__(256) void ln_kernel(const float* __restrict__ x,
                                                 const float* __restrict__ g,
                                                 const float* __restrict__ b,
                                                 u16* __restrict__ xn) {
  const int row = blockIdx.x;
  const int tid = threadIdx.x;
  const float4 v = reinterpret_cast<const float4*>(x + (size_t)row * DD)[tid];
  float s = v.x + v.y + v.z + v.w;
  float s2 = v.x * v.x + v.y * v.y + v.z * v.z + v.w * v.w;
#pragma unroll
  for (int o = 32; o > 0; o >>= 1) { s += __shfl_down(s, o); s2 += __shfl_down(s2, o); }
  __shared__ float red[8];
  const int wv = tid >> 6;
  if ((tid & 63) == 0) { red[wv] = s; red[4 + wv] = s2; }
  __syncthreads();
  s = red[0] + red[1] + red[2] + red[3];
  s2 = red[4] + red[5] + red[6] + red[7];
  const float mu = s * (1.f / 1024.f);
  const float var = s2 * (1.f / 1024.f) - mu * mu;
  const float rstd = rsqrtf(var + 1e-5f);
  const float4 gg = reinterpret_cast<const float4*>(g)[tid];
  const float4 bb = reinterpret_cast<const float4*>(b)[tid];
  us4 o4;
  o4.x = f2bf((v.x - mu) * rstd * gg.x + bb.x);
  o4.y = f2bf((v.y - mu) * rstd * gg.y + bb.y);
  o4.z = f2bf((v.z - mu) * rstd * gg.z + bb.z);
  o4.w = f2bf((v.w - mu) * rstd * gg.w + bb.w);
  *reinterpret_cast<us4*>(xn + (size_t)row * DD + tid * 4) = o4;
}

// ---------------- bf16 MFMA GEMM: C = A(MxK) @ BT(NxK)^T, epilogue per EPI ----------------
// EPI: 0 = store bf16, 1 = store f32, 2 = sigmoid f32, 3 = bias + (1-sigmoid) f32
template <int EPI>
__global__ __launch_bounds__(256) void gemm_bt(const u16* __restrict__ A,
                                               const u16* __restrict__ BT,
                                               float* __restrict__ Cf,
                                               u16* __restrict__ Cb,
                                               const float* __restrict__ bias,
                                               int M, int N, int K) {
  __shared__ u16 lA[2][128 * 32];
  __shared__ u16 lB[2][128 * 32];
  const int tid = threadIdx.x;
  const int bx = blockIdx.x, by = blockIdx.y;
  const int lane = tid & 63, wid = tid >> 6;
  const int wr = wid >> 1, wc = wid & 1;
  const int sr = tid >> 2, sc = (tid & 3) * 8;
  const u16* gA = A + (size_t)(by * 128 + sr) * K + sc;
  const u16* gB = BT + (size_t)(bx * 128 + sr) * K + sc;

  f32x4 acc[4][4];
#pragma unroll
  for (int m = 0; m < 4; ++m)
#pragma unroll
    for (int n = 0; n < 4; ++n) acc[m][n] = (f32x4){0.f, 0.f, 0.f, 0.f};

  auto stage = [&](int buf, int kt) {
    const u16* a0 = gA + kt * 32;
    const u16* b0 = gB + kt * 32;
    gload16(a0, &lA[buf][tid * 8]);
    gload16(a0 + (size_t)64 * K, &lA[buf][2048 + tid * 8]);
    gload16(b0, &lB[buf][tid * 8]);
    gload16(b0 + (size_t)64 * K, &lB[buf][2048 + tid * 8]);
  };

  stage(0, 0);
  const int fr = lane & 15, fk = (lane >> 4) * 8;
  int cur = 0;
  const int nk = K / 32;
  for (int kt = 0; kt < nk; ++kt) {
    __syncthreads();
    if (kt + 1 < nk) stage(cur ^ 1, kt + 1);
    short8 af[4], bv[4];
#pragma unroll
    for (int m = 0; m < 4; ++m)
      af[m] = *reinterpret_cast<const short8*>(&lA[cur][(wr * 64 + m * 16 + fr) * 32 + fk]);
#pragma unroll
    for (int n = 0; n < 4; ++n)
      bv[n] = *reinterpret_cast<const short8*>(&lB[cur][(wc * 64 + n * 16 + fr) * 32 + fk]);
#pragma unroll
    for (int m = 0; m < 4; ++m)
#pragma unroll
      for (int n = 0; n < 4; ++n)
        acc[m][n] = __builtin_amdgcn_mfma_f32_16x16x32_bf16(af[m], bv[n], acc[m][n], 0, 0, 0);
    cur ^= 1;
  }

  const int er = (lane >> 4) * 4, ec = lane & 15;
#pragma unroll
  for (int m = 0; m < 4; ++m) {
    const int row0 = by * 128 + wr * 64 + m * 16 + er;
#pragma unroll
    for (int n = 0; n < 4; ++n) {
      const int col = bx * 128 + wc * 64 + n * 16 + ec;
#pragma unroll
      for (int i = 0; i < 4; ++i) {
        const float val = acc[m][n][i];
        const size_t idx = (size_t)(row0 + i) * N + col;
        if constexpr (EPI == 0) {
          Cb[idx] = f2bf(val);
        } else if constexpr (EPI == 1) {
          Cf[idx] = val;
        } else if constexpr (EPI == 2) {
          Cf[idx] = 1.f / (1.f + __expf(-val));
        } else {
          const float z = val + bias[col];
          Cf[idx] = 1.f / (1.f + __expf(z));   // 1 - sigmoid(z)
        }
      }
    }
  }
}

// ---------------- chunked scan, phase 1: per-chunk decay product P and zero-init state U ----
// grid (NC, 64 chains), 256 threads = 4 waves; wave w owns d in [16w,16w+16); barrier-free
__global__ __launch_bounds__(256) void scan_phase1(const float* __restrict__ omw,
                                                   const float* __restrict__ kk,
                                                   const float* __restrict__ vv,
                                                   u16* __restrict__ U,
                                                   float* __restrict__ P) {
  const int c = blockIdx.x, bh = blockIdx.y;
  const int tid = threadIdx.x;
  const int lane = tid & 63;                                    // e
  const int dbase = __builtin_amdgcn_readfirstlane((tid >> 6) << 4);
  const size_t chainBase = (size_t)(bh >> 4) * TT * DD + (size_t)(bh & 15) * HS;
  size_t base = chainBase + (size_t)c * CH * DD;

  float st[16];
#pragma unroll
  for (int i = 0; i < 16; ++i) st[i] = 0.f;
  const int pd = dbase + (lane & 15);
  float vp = 1.f;

  float ve = vv[base + lane];
  for (int t = 0; t < CH; ++t) {
    const float* __restrict__ op = omw + base;  // uniform + dbase -> s_load_dwordx16
    const float* __restrict__ kp = kk + base;
    const size_t nbase = (t + 1 < CH) ? (base + DD) : base;
    const float ve_n = vv[nbase + lane];
    vp *= op[pd];                                // per-lane vector load (16 uniq addrs)
#pragma unroll
    for (int i = 0; i < 16; ++i)
      st[i] = __builtin_fmaf(op[dbase + i], st[i], kp[dbase + i] * ve);
    ve = ve_n;
    base += DD;
  }
  u16* __restrict__ Ub = U + ((size_t)c * 64 + bh) * 4096;
#pragma unroll
  for (int i = 0; i < 16; ++i) Ub[(dbase + i) * 64 + lane] = f2bf(st[i]);
  if (lane < 16) P[((size_t)c * 64 + bh) * 64 + dbase + lane] = vp;
}

// ---------------- phase 2: sequential combine over chunks (in-place: U becomes S_start) ----
// grid (64 chains, 16 d-slices), 256 threads; thread owns one (d,e) element; fp32 accum
__global__ __launch_bounds__(256) void scan_phase2(u16* __restrict__ U,
                                                   const float* __restrict__ P,
                                                   float* __restrict__ stateOut) {
  const int bh = blockIdx.x;
  const int ds = blockIdx.y;
  const int tid = threadIdx.x;
  const int d = ds * 4 + (tid >> 6);   // wave-uniform
  const int e = tid & 63;
  const size_t el = (size_t)d * 64 + e;

  float S = 0.f;
  size_t ub = (size_t)bh * 4096 + el;
  size_t pb = (size_t)bh * 64 + d;
  u16 u_c = U[ub];
  float p_c = P[pb];
  for (int c = 0; c < NC; ++c) {
    u16 u_n = u_c; float p_n = p_c;
    if (c + 1 < NC) {                        // prefetch next chunk's inputs
      u_n = U[ub + (size_t)64 * 4096];
      p_n = P[pb + (size_t)64 * 64];
    }
    U[ub] = f2bf(S);                         // chunk-start state (S_start)
    S = __builtin_fmaf(p_c, S, bf2f(u_c));
    u_c = u_n; p_c = p_n;
    ub += (size_t)64 * 4096;
    pb += (size_t)64 * 64;
  }
  stateOut[(size_t)bh * 4096 + el] = S;   // final state (output 1)
}

// ---------------- phase 3: re-run chunk from true initial state, emit outputs ----------------
// grid (NC, 64 chains), 256 threads = 4 waves; wave w owns d in [16w,16w+16).
// Output partials go to per-wave LDS slots; block reduces once per 16-step window
// (2 barriers per window, 4 per chunk — NOT per step).
__global__ __launch_bounds__(256) void scan_phase3(const float* __restrict__ omw,
                                                   const float* __restrict__ kk,
                                                   const float* __restrict__ vv,
                                                   const float* __restrict__ rr,
                                                   const u16* __restrict__ S_start,
                                                   u16* __restrict__ outs) {
  __shared__ float part[4][16][64];          // 16 KB
  const int c = blockIdx.x, bh = blockIdx.y;
  const int tid = threadIdx.x;
  const int lane = tid & 63;                 // e
  const int wid = tid >> 6;
  const int dbase = __builtin_amdgcn_readfirstlane(wid << 4);
  const size_t chainBase = (size_t)(bh >> 4) * TT * DD + (size_t)(bh & 15) * HS;
  const size_t base0 = chainBase + (size_t)c * CH * DD;
  size_t base = base0;

  float st[16];
  const u16* __restrict__ Sb = S_start + ((size_t)c * 64 + bh) * 4096;
#pragma unroll
  for (int i = 0; i < 16; ++i) st[i] = bf2f(Sb[(dbase + i) * 64 + lane]);

  float ve = vv[base + lane];
  for (int w2 = 0; w2 < CH / 16; ++w2) {
#pragma unroll
    for (int tt = 0; tt < 16; ++tt) {
      const float* __restrict__ op = omw + base;   // s_load_dwordx16 slices
      const float* __restrict__ kp = kk + base;
      const float* __restrict__ rp = rr + base;
      const size_t nbase = (w2 * 16 + tt + 1 < CH) ? (base + DD) : base;
      const float ve_n = vv[nbase + lane];

      float a0 = 0.f, a1 = 0.f;
#pragma unroll
      for (int i = 0; i < 8; ++i) {
        st[i] = __builtin_fmaf(op[dbase + i], st[i], kp[dbase + i] * ve);
        a0 = __builtin_fmaf(rp[dbase + i], st[i], a0);
        st[8 + i] = __builtin_fmaf(op[dbase + 8 + i], st[8 + i], kp[dbase + 8 + i] * ve);
        a1 = __builtin_fmaf(rp[dbase + 8 + i], st[8 + i], a1);
      }
      part[wid][tt][lane] = a0 + a1;
      ve = ve_n;
      base += DD;
    }
    __syncthreads();
    // reduce 16 steps across 4 waves: wave handles 4 steps
#pragma unroll
    for (int s = 0; s < 4; ++s) {
      const int tt = wid * 4 + s;
      const float sum = (part[0][tt][lane] + part[1][tt][lane]) +
                        (part[2][tt][lane] + part[3][tt][lane]);
      outs[base0 + (size_t)(w2 * 16 + tt) * DD + lane] = f2bf(sum);
    }
    __syncthreads();
  }
}

extern "C" void kernel_launch(void* const* d_in, const int* in_sizes, int n_in,
                              void* d_out, int out_size, void* d_ws, size_t ws_size,
                              hipStream_t stream) {
  const float* x   = (const float*)d_in[0];
  const float* lng = (const float*)d_in[1];
  const float* lnb = (const float*)d_in[2];
  const float* Wx  = (const float*)d_in[3];
  const float* Ww  = (const float*)d_in[4];
  const float* bw  = (const float*)d_in[5];
  const float* Wk  = (const float*)d_in[6];
  const float* Wv  = (const float*)d_in[7];
  const float* Wr  = (const float*)d_in[8];
  const float* Wo  = (const float*)d_in[9];
  float* out = (float*)d_out;
  char* ws = (char*)d_ws;

  // ---- workspace layout: total 188 MiB, identical to the proven round-1 footprint ----
  const size_t SZ_W = (size_t)DD * DD * 2;       // 2 MB bf16 weight
  u16* WxT = (u16*)(ws + 0 * SZ_W);
  u16* WwT = (u16*)(ws + 1 * SZ_W);
  u16* WkT = (u16*)(ws + 2 * SZ_W);
  u16* WvT = (u16*)(ws + 3 * SZ_W);
  u16* WrT = (u16*)(ws + 4 * SZ_W);
  u16* WoT = (u16*)(ws + 5 * SZ_W);
  size_t off = 6 * SZ_W;
  const size_t SZ_ABF = (size_t)ROWS * DD * 2;   // 16 MB bf16 activation
  u16* xn   = (u16*)(ws + off); off += SZ_ABF;
  u16* pbuf = (u16*)(ws + off); off += SZ_ABF;
  u16* outs = (u16*)(ws + off); off += SZ_ABF;
  const size_t SZ_AF = (size_t)ROWS * DD * 4;    // 32 MB f32 activation
  float* omw = (float*)(ws + off); off += SZ_AF;
  float* kf  = (float*)(ws + off); off += SZ_AF;
  float* vf  = (float*)(ws + off); off += SZ_AF;
  float* rf  = (float*)(ws + off); off += SZ_AF;
  // scan scratch ALIASES dead buffers (no growth past 188 MiB):
  //  Ubuf bf16 (NC*64*4096*2 = 32 MiB) -> xn+pbuf region (dead after last projection
  //    GEMM; rewritten by ln_kernel every call, so graph-replay safe)
  //  Pbuf fp32 (NC*64*64*4 = 1 MiB)    -> WxT region (dead after GEMM 1)
  u16*   Ubuf = xn;
  float* Pbuf = (float*)WxT;
  (void)ws_size; (void)in_sizes; (void)n_in; (void)out_size;

  dim3 tpb(32, 8), tgrid(32, 32);
  transpose_cast<<<tgrid, tpb, 0, stream>>>(Wx, WxT);
  transpose_cast<<<tgrid, tpb, 0, stream>>>(Ww, WwT);
  transpose_cast<<<tgrid, tpb, 0, stream>>>(Wk, WkT);
  transpose_cast<<<tgrid, tpb, 0, stream>>>(Wv, WvT);
  transpose_cast<<<tgrid, tpb, 0, stream>>>(Wr, WrT);
  transpose_cast<<<tgrid, tpb, 0, stream>>>(Wo, WoT);

  ln_kernel<<<ROWS, 256, 0, stream>>>(x, lng, lnb, xn);

  dim3 ggrid(DD / 128, ROWS / 128), gblk(256);
  // p = xn @ Wx  (bf16)
  gemm_bt<0><<<ggrid, gblk, 0, stream>>>(xn, WxT, nullptr, pbuf, nullptr, ROWS, DD, DD);
  // omw = 1 - sigmoid(p @ Ww + bw)  (f32)
  gemm_bt<3><<<ggrid, gblk, 0, stream>>>(pbuf, WwT, omw, nullptr, bw, ROWS, DD, DD);
  // k, v (f32); r = sigmoid (f32)
  gemm_bt<1><<<ggrid, gblk, 0, stream>>>(xn, WkT, kf, nullptr, nullptr, ROWS, DD, DD);
  gemm_bt<1><<<ggrid, gblk, 0, stream>>>(xn, WvT, vf, nullptr, nullptr, ROWS, DD, DD);
  gemm_bt<2><<<ggrid, gblk, 0, stream>>>(xn, WrT, rf, nullptr, nullptr, ROWS, DD, DD);

  // chunked scan (xn/pbuf/WxT are dead from here on; their memory hosts Ubuf/Pbuf)
  dim3 sgrid(NC, 64);
  scan_phase1<<<sgrid, 256, 0, stream>>>(omw, kf, vf, Ubuf, Pbuf);
  dim3 p2grid(64, 16);
  scan_phase2<<<p2grid, 256, 0, stream>>>(Ubuf, Pbuf, out + (size_t)ROWS * DD);
  scan_phase3<<<sgrid, 256, 0, stream>>>(omw, kf, vf, rf, Ubuf, outs);

  // y = outs @ Wo (f32, first output)
  gemm_bt<1><<<ggrid, gblk, 0, stream>>>(outs, WoT, out, nullptr, nullptr, ROWS, DD, DD);
}

// Round 17
// 473.231 us; speedup vs baseline: 7.8668x; 1.0476x over previous
//
#include <hip/hip_runtime.h>

#define ROWS 8192   // B*T
#define DD   1024   // d_model
#define TT   2048   // T
#define NH   16     // heads
#define HS   64     // head size
#define CH   32     // scan chunk length
#define NC   (TT / CH)   // 64 chunks

typedef __attribute__((ext_vector_type(8))) short short8;
typedef __attribute__((ext_vector_type(4))) float f32x4;
typedef __attribute__((ext_vector_type(4))) unsigned short us4;
typedef unsigned short u16;

__device__ __forceinline__ u16 f2bf(float f) {
  unsigned u = __builtin_bit_cast(unsigned, f);
  u += 0x7fffu + ((u >> 16) & 1u);   // round-to-nearest-even
  return (u16)(u >> 16);
}

__device__ __forceinline__ float bf2f(u16 h) {
  return __builtin_bit_cast(float, (unsigned)h << 16);
}

__device__ __forceinline__ void gload16(const void* g, void* l) {
  __builtin_amdgcn_global_load_lds(
      (const __attribute__((address_space(1))) unsigned int*)g,
      (__attribute__((address_space(3))) unsigned int*)l, 16, 0, 0);
}

// ---------------- transpose + cast to bf16: WT[n][k] = bf16(W[k][n]) ----------------
__global__ __launch_bounds__(256) void transpose_cast(const float* __restrict__ W,
                                                      u16* __restrict__ WT) {
  __shared__ float tile[32][33];
  const int tx = threadIdx.x, ty = threadIdx.y;
  const int bx = blockIdx.x, by = blockIdx.y;
#pragma unroll
  for (int j = 0; j < 4; ++j)
    tile[ty + j * 8][tx] = W[(size_t)(by * 32 + ty + j * 8) * DD + bx * 32 + tx];
  __syncthreads();
#pragma unroll
  for (int j = 0; j < 4; ++j)
    WT[(size_t)(bx * 32 + ty + j * 8) * DD + by * 32 + tx] = f2bf(tile[tx][ty + j * 8]);
}

// ---------------- LayerNorm (pop. variance) + cast to bf16 ----------------
__global__ __launch_bounds__(256) void ln_kernel(const float* __restrict__ x,
                                                 const float* __restrict__ g,
                                                 const float* __restrict__ b,
                                                 u16* __restrict__ xn) {
  const int row = blockIdx.x;
  const int tid = threadIdx.x;
  const float4 v = reinterpret_cast<const float4*>(x + (size_t)row * DD)[tid];
  float s = v.x + v.y + v.z + v.w;
  float s2 = v.x * v.x + v.y * v.y + v.z * v.z + v.w * v.w;
#pragma unroll
  for (int o = 32; o > 0; o >>= 1) { s += __shfl_down(s, o); s2 += __shfl_down(s2, o); }
  __shared__ float red[8];
  const int wv = tid >> 6;
  if ((tid & 63) == 0) { red[wv] = s; red[4 + wv] = s2; }
  __syncthreads();
  s = red[0] + red[1] + red[2] + red[3];
  s2 = red[4] + red[5] + red[6] + red[7];
  const float mu = s * (1.f / 1024.f);
  const float var = s2 * (1.f / 1024.f) - mu * mu;
  const float rstd = rsqrtf(var + 1e-5f);
  const float4 gg = reinterpret_cast<const float4*>(g)[tid];
  const float4 bb = reinterpret_cast<const float4*>(b)[tid];
  us4 o4;
  o4.x = f2bf((v.x - mu) * rstd * gg.x + bb.x);
  o4.y = f2bf((v.y - mu) * rstd * gg.y + bb.y);
  o4.z = f2bf((v.z - mu) * rstd * gg.z + bb.z);
  o4.w = f2bf((v.w - mu) * rstd * gg.w + bb.w);
  *reinterpret_cast<us4*>(xn + (size_t)row * DD + tid * 4) = o4;
}

// ---------------- bf16 MFMA GEMM: C = A(MxK) @ BT(NxK)^T, epilogue per EPI ----------------
// EPI: 0 = store bf16, 1 = store f32, 2 = sigmoid f32, 3 = bias + (1-sigmoid) f32
template <int EPI>
__global__ __launch_bounds__(256) void gemm_bt(const u16* __restrict__ A,
                                               const u16* __restrict__ BT,
                                               float* __restrict__ Cf,
                                               u16* __restrict__ Cb,
                                               const float* __restrict__ bias,
                                               int M, int N, int K) {
  __shared__ u16 lA[2][128 * 32];
  __shared__ u16 lB[2][128 * 32];
  const int tid = threadIdx.x;
  const int bx = blockIdx.x, by = blockIdx.y;
  const int lane = tid & 63, wid = tid >> 6;
  const int wr = wid >> 1, wc = wid & 1;
  const int sr = tid >> 2, sc = (tid & 3) * 8;
  const u16* gA = A + (size_t)(by * 128 + sr) * K + sc;
  const u16* gB = BT + (size_t)(bx * 128 + sr) * K + sc;

  f32x4 acc[4][4];
#pragma unroll
  for (int m = 0; m < 4; ++m)
#pragma unroll
    for (int n = 0; n < 4; ++n) acc[m][n] = (f32x4){0.f, 0.f, 0.f, 0.f};

  auto stage = [&](int buf, int kt) {
    const u16* a0 = gA + kt * 32;
    const u16* b0 = gB + kt * 32;
    gload16(a0, &lA[buf][tid * 8]);
    gload16(a0 + (size_t)64 * K, &lA[buf][2048 + tid * 8]);
    gload16(b0, &lB[buf][tid * 8]);
    gload16(b0 + (size_t)64 * K, &lB[buf][2048 + tid * 8]);
  };

  stage(0, 0);
  const int fr = lane & 15, fk = (lane >> 4) * 8;
  int cur = 0;
  const int nk = K / 32;
  for (int kt = 0; kt < nk; ++kt) {
    __syncthreads();
    if (kt + 1 < nk) stage(cur ^ 1, kt + 1);
    short8 af[4], bv[4];
#pragma unroll
    for (int m = 0; m < 4; ++m)
      af[m] = *reinterpret_cast<const short8*>(&lA[cur][(wr * 64 + m * 16 + fr) * 32 + fk]);
#pragma unroll
    for (int n = 0; n < 4; ++n)
      bv[n] = *reinterpret_cast<const short8*>(&lB[cur][(wc * 64 + n * 16 + fr) * 32 + fk]);
#pragma unroll
    for (int m = 0; m < 4; ++m)
#pragma unroll
      for (int n = 0; n < 4; ++n)
        acc[m][n] = __builtin_amdgcn_mfma_f32_16x16x32_bf16(af[m], bv[n], acc[m][n], 0, 0, 0);
    cur ^= 1;
  }

  const int er = (lane >> 4) * 4, ec = lane & 15;
#pragma unroll
  for (int m = 0; m < 4; ++m) {
    const int row0 = by * 128 + wr * 64 + m * 16 + er;
#pragma unroll
    for (int n = 0; n < 4; ++n) {
      const int col = bx * 128 + wc * 64 + n * 16 + ec;
#pragma unroll
      for (int i = 0; i < 4; ++i) {
        const float val = acc[m][n][i];
        const size_t idx = (size_t)(row0 + i) * N + col;
        if constexpr (EPI == 0) {
          Cb[idx] = f2bf(val);
        } else if constexpr (EPI == 1) {
          Cf[idx] = val;
        } else if constexpr (EPI == 2) {
          Cf[idx] = 1.f / (1.f + __expf(-val));
        } else {
          const float z = val + bias[col];
          Cf[idx] = 1.f / (1.f + __expf(z));   // 1 - sigmoid(z)
        }
      }
    }
  }
}

// ---------------- chunked scan, phase 1 ----------------
// grid (NC, 64 chains), 256 threads = 4 waves; wave w owns d in [16w,16w+16).
// op/kp/vv staged per 16-step window into LDS via global_load_lds (double-buffered);
// compute reads LDS broadcasts — NO wave-uniform scalar-load chains.
__global__ __launch_bounds__(256) void scan_phase1(const float* __restrict__ omw,
                                                   const float* __restrict__ kk,
                                                   const float* __restrict__ vv,
                                                   u16* __restrict__ U,
                                                   float* __restrict__ P) {
  __shared__ float win[2 * 3072];            // 2 bufs x {op,kp,vv} x 16 steps x 64 = 24 KB
  const int c = blockIdx.x, bh = blockIdx.y;
  const int tid = threadIdx.x;
  const int lane = tid & 63;
  const int wid = tid >> 6;
  const int dbase = __builtin_amdgcn_readfirstlane(wid << 4);
  const size_t chainBase = (size_t)(bh >> 4) * TT * DD + (size_t)(bh & 15) * HS;
  const size_t base0 = chainBase + (size_t)c * CH * DD;

  auto stage = [&](int buf, int w2) {
#pragma unroll
    for (int j = 0; j < 3; ++j) {
      const int idx = tid + 256 * j;          // (a, tt, f4c): a=idx>>8 uniform per (wave,j)
      const int a = idx >> 8, rem = idx & 255, tt = rem >> 4, f4c = rem & 15;
      const float* s = (a == 0) ? omw : (a == 1) ? kk : vv;
      gload16(s + base0 + (size_t)(w2 * 16 + tt) * DD + f4c * 4,
              &win[buf * 3072 + idx * 4]);    // dest = wave-uniform base + lane*16
    }
  };

  float st[16];
#pragma unroll
  for (int i = 0; i < 16; ++i) st[i] = 0.f;
  const int pd = dbase + (lane & 15);
  float vp = 1.f;

  stage(0, 0);
  __syncthreads();                            // drains vmcnt -> buf0 ready
  int buf = 0;
  for (int w2 = 0; w2 < CH / 16; ++w2) {
    if (w2 + 1 < CH / 16) stage(buf ^ 1, w2 + 1);
    const float* wb = &win[buf * 3072];
#pragma unroll
    for (int tt = 0; tt < 16; ++tt) {
      const float4* o4 = (const float4*)&wb[       tt * 64 + dbase];  // broadcast reads
      const float4* k4 = (const float4*)&wb[1024 + tt * 64 + dbase];
      const float ve  = wb[2048 + tt * 64 + lane];                    // per-lane, stride 1
      vp *= wb[tt * 64 + pd];
#pragma unroll
      for (int i4 = 0; i4 < 4; ++i4) {
        const float4 o = o4[i4], k = k4[i4];
        st[4*i4+0] = __builtin_fmaf(o.x, st[4*i4+0], k.x * ve);
        st[4*i4+1] = __builtin_fmaf(o.y, st[4*i4+1], k.y * ve);
        st[4*i4+2] = __builtin_fmaf(o.z, st[4*i4+2], k.z * ve);
        st[4*i4+3] = __builtin_fmaf(o.w, st[4*i4+3], k.w * ve);
      }
    }
    __syncthreads();                          // reads of buf done; next buf loaded
    buf ^= 1;
  }
  u16* __restrict__ Ub = U + ((size_t)c * 64 + bh) * 4096;
#pragma unroll
  for (int i = 0; i < 16; ++i) Ub[(dbase + i) * 64 + lane] = f2bf(st[i]);
  if (lane < 16) P[((size_t)c * 64 + bh) * 64 + dbase + lane] = vp;
}

// ---------------- phase 2: sequential combine over chunks (in-place: U becomes S_start) ----
// grid (64 chains, 16 d-slices), 256 threads; thread owns one (d,e) element; fp32 accum
__global__ __launch_bounds__(256) void scan_phase2(u16* __restrict__ U,
                                                   const float* __restrict__ P,
                                                   float* __restrict__ stateOut) {
  const int bh = blockIdx.x;
  const int ds = blockIdx.y;
  const int tid = threadIdx.x;
  const int d = ds * 4 + (tid >> 6);   // wave-uniform
  const int e = tid & 63;
  const size_t el = (size_t)d * 64 + e;

  float S = 0.f;
  size_t ub = (size_t)bh * 4096 + el;
  size_t pb = (size_t)bh * 64 + d;
  u16 u_c = U[ub];
  float p_c = P[pb];
  for (int c = 0; c < NC; ++c) {
    u16 u_n = u_c; float p_n = p_c;
    if (c + 1 < NC) {                        // prefetch next chunk's inputs
      u_n = U[ub + (size_t)64 * 4096];
      p_n = P[pb + (size_t)64 * 64];
    }
    U[ub] = f2bf(S);                         // chunk-start state (S_start)
    S = __builtin_fmaf(p_c, S, bf2f(u_c));
    u_c = u_n; p_c = p_n;
    ub += (size_t)64 * 4096;
    pb += (size_t)64 * 64;
  }
  stateOut[(size_t)bh * 4096 + el] = S;   // final state (output 1)
}

// ---------------- phase 3: re-run chunk from true initial state, emit outputs ----------------
// grid (NC, 64 chains), 256 threads = 4 waves; wave w owns d in [16w,16w+16).
// op/kp/rp/vv staged per 16-step window into LDS (double-buffered, global_load_lds);
// output partials to per-wave LDS, reduce once per window (2 barriers / 16 steps).
__global__ __launch_bounds__(256) void scan_phase3(const float* __restrict__ omw,
                                                   const float* __restrict__ kk,
                                                   const float* __restrict__ vv,
                                                   const float* __restrict__ rr,
                                                   const u16* __restrict__ S_start,
                                                   u16* __restrict__ outs) {
  __shared__ float win[2 * 4096];            // 2 bufs x {op,kp,rp,vv} x 16 x 64 = 32 KB
  __shared__ float part[4][16][64];          // 16 KB
  const int c = blockIdx.x, bh = blockIdx.y;
  const int tid = threadIdx.x;
  const int lane = tid & 63;                 // e
  const int wid = tid >> 6;
  const int dbase = __builtin_amdgcn_readfirstlane(wid << 4);
  const size_t chainBase = (size_t)(bh >> 4) * TT * DD + (size_t)(bh & 15) * HS;
  const size_t base0 = chainBase + (size_t)c * CH * DD;

  auto stage = [&](int buf, int w2) {
#pragma unroll
    for (int j = 0; j < 4; ++j) {
      const int idx = tid + 256 * j;          // (a, tt, f4c): a uniform per (wave,j)
      const int a = idx >> 8, rem = idx & 255, tt = rem >> 4, f4c = rem & 15;
      const float* s = (a == 0) ? omw : (a == 1) ? kk : (a == 2) ? rr : vv;
      gload16(s + base0 + (size_t)(w2 * 16 + tt) * DD + f4c * 4,
              &win[buf * 4096 + idx * 4]);
    }
  };

  float st[16];
  const u16* __restrict__ Sb = S_start + ((size_t)c * 64 + bh) * 4096;
#pragma unroll
  for (int i = 0; i < 16; ++i) st[i] = bf2f(Sb[(dbase + i) * 64 + lane]);

  stage(0, 0);
  __syncthreads();
  int buf = 0;
  for (int w2 = 0; w2 < CH / 16; ++w2) {
    if (w2 + 1 < CH / 16) stage(buf ^ 1, w2 + 1);
    const float* wb = &win[buf * 4096];
#pragma unroll
    for (int tt = 0; tt < 16; ++tt) {
      const float4* o4 = (const float4*)&wb[       tt * 64 + dbase];
      const float4* k4 = (const float4*)&wb[1024 + tt * 64 + dbase];
      const float4* r4 = (const float4*)&wb[2048 + tt * 64 + dbase];
      const float ve  = wb[3072 + tt * 64 + lane];
      float a0 = 0.f, a1 = 0.f;
#pragma unroll
      for (int i4 = 0; i4 < 4; ++i4) {
        const float4 o = o4[i4], k = k4[i4], r = r4[i4];
        st[4*i4+0] = __builtin_fmaf(o.x, st[4*i4+0], k.x * ve);
        a0 = __builtin_fmaf(r.x, st[4*i4+0], a0);
        st[4*i4+1] = __builtin_fmaf(o.y, st[4*i4+1], k.y * ve);
        a1 = __builtin_fmaf(r.y, st[4*i4+1], a1);
        st[4*i4+2] = __builtin_fmaf(o.z, st[4*i4+2], k.z * ve);
        a0 = __builtin_fmaf(r.z, st[4*i4+2], a0);
        st[4*i4+3] = __builtin_fmaf(o.w, st[4*i4+3], k.w * ve);
        a1 = __builtin_fmaf(r.w, st[4*i4+3], a1);
      }
      part[wid][tt][lane] = a0 + a1;
    }
    __syncthreads();                          // partials visible; next buf loaded
#pragma unroll
    for (int s = 0; s < 4; ++s) {
      const int tt = wid * 4 + s;
      const float sum = (part[0][tt][lane] + part[1][tt][lane]) +
                        (part[2][tt][lane] + part[3][tt][lane]);
      outs[base0 + (size_t)(w2 * 16 + tt) * DD + lane] = f2bf(sum);
    }
    __syncthreads();                          // part reusable
    buf ^= 1;
  }
}

extern "C" void kernel_launch(void* const* d_in, const int* in_sizes, int n_in,
                              void* d_out, int out_size, void* d_ws, size_t ws_size,
                              hipStream_t stream) {
  const float* x   = (const float*)d_in[0];
  const float* lng = (const float*)d_in[1];
  const float* lnb = (const float*)d_in[2];
  const float* Wx  = (const float*)d_in[3];
  const float* Ww  = (const float*)d_in[4];
  const float* bw  = (const float*)d_in[5];
  const float* Wk  = (const float*)d_in[6];
  const float* Wv  = (const float*)d_in[7];
  const float* Wr  = (const float*)d_in[8];
  const float* Wo  = (const float*)d_in[9];
  float* out = (float*)d_out;
  char* ws = (char*)d_ws;

  // ---- workspace layout: total 188 MiB, identical to the proven round-1 footprint ----
  const size_t SZ_W = (size_t)DD * DD * 2;       // 2 MB bf16 weight
  u16* WxT = (u16*)(ws + 0 * SZ_W);
  u16* WwT = (u16*)(ws + 1 * SZ_W);
  u16* WkT = (u16*)(ws + 2 * SZ_W);
  u16* WvT = (u16*)(ws + 3 * SZ_W);
  u16* WrT = (u16*)(ws + 4 * SZ_W);
  u16* WoT = (u16*)(ws + 5 * SZ_W);
  size_t off = 6 * SZ_W;
  const size_t SZ_ABF = (size_t)ROWS * DD * 2;   // 16 MB bf16 activation
  u16* xn   = (u16*)(ws + off); off += SZ_ABF;
  u16* pbuf = (u16*)(ws + off); off += SZ_ABF;
  u16* outs = (u16*)(ws + off); off += SZ_ABF;
  const size_t SZ_AF = (size_t)ROWS * DD * 4;    // 32 MB f32 activation
  float* omw = (float*)(ws + off); off += SZ_AF;
  float* kf  = (float*)(ws + off); off += SZ_AF;
  float* vf  = (float*)(ws + off); off += SZ_AF;
  float* rf  = (float*)(ws + off); off += SZ_AF;
  // scan scratch ALIASES dead buffers (no growth past 188 MiB):
  //  Ubuf bf16 (NC*64*4096*2 = 32 MiB) -> xn+pbuf region (dead after last projection
  //    GEMM; rewritten by ln_kernel every call, so graph-replay safe)
  //  Pbuf fp32 (NC*64*64*4 = 1 MiB)    -> WxT region (dead after GEMM 1)
  u16*   Ubuf = xn;
  float* Pbuf = (float*)WxT;
  (void)ws_size; (void)in_sizes; (void)n_in; (void)out_size;

  dim3 tpb(32, 8), tgrid(32, 32);
  transpose_cast<<<tgrid, tpb, 0, stream>>>(Wx, WxT);
  transpose_cast<<<tgrid, tpb, 0, stream>>>(Ww, WwT);
  transpose_cast<<<tgrid, tpb, 0, stream>>>(Wk, WkT);
  transpose_cast<<<tgrid, tpb, 0, stream>>>(Wv, WvT);
  transpose_cast<<<tgrid, tpb, 0, stream>>>(Wr, WrT);
  transpose_cast<<<tgrid, tpb, 0, stream>>>(Wo, WoT);

  ln_kernel<<<ROWS, 256, 0, stream>>>(x, lng, lnb, xn);

  dim3 ggrid(DD / 128, ROWS / 128), gblk(256);
  // p = xn @ Wx  (bf16)
  gemm_bt<0><<<ggrid, gblk, 0, stream>>>(xn, WxT, nullptr, pbuf, nullptr, ROWS, DD, DD);
  // omw = 1 - sigmoid(p @ Ww + bw)  (f32)
  gemm_bt<3><<<ggrid, gblk, 0, stream>>>(pbuf, WwT, omw, nullptr, bw, ROWS, DD, DD);
  // k, v (f32); r = sigmoid (f32)
  gemm_bt<1><<<ggrid, gblk, 0, stream>>>(xn, WkT, kf, nullptr, nullptr, ROWS, DD, DD);
  gemm_bt<1><<<ggrid, gblk, 0, stream>>>(xn, WvT, vf, nullptr, nullptr, ROWS, DD, DD);
  gemm_bt<2><<<ggrid, gblk, 0, stream>>>(xn, WrT, rf, nullptr, nullptr, ROWS, DD, DD);

  // chunked scan (xn/pbuf/WxT are dead from here on; their memory hosts Ubuf/Pbuf)
  dim3 sgrid(NC, 64);
  scan_phase1<<<sgrid, 256, 0, stream>>>(omw, kf, vf, Ubuf, Pbuf);
  dim3 p2grid(64, 16);
  scan_phase2<<<p2grid, 256, 0, stream>>>(Ubuf, Pbuf, out + (size_t)ROWS * DD);
  scan_phase3<<<sgrid, 256, 0, stream>>>(omw, kf, vf, rf, Ubuf, outs);

  // y = outs @ Wo (f32, first output)
  gemm_bt<1><<<ggrid, gblk, 0, stream>>>(outs, WoT, out, nullptr, nullptr, ROWS, DD, DD);
}